// Round 2
// baseline (6383.150 us; speedup 1.0000x reference)
//
#include <hip/hip_runtime.h>
#include <hip/hip_bf16.h>

#define BN_EPS 1e-5f

// ---------------------------------------------------------------------------
// scatter-add: agg[dst[e]] += h[src[e]], C columns (C4 = C/4 float4 chunks)
// ---------------------------------------------------------------------------
template <int C4>
__global__ void scatter_add_kernel(const float* __restrict__ h,
                                   const int* __restrict__ src,
                                   const int* __restrict__ dst,
                                   float* __restrict__ agg,
                                   int total /* = E * C4 */) {
    int i = blockIdx.x * blockDim.x + threadIdx.x;
    if (i >= total) return;
    int e = i / C4;
    int c = (i - e * C4) * 4;
    int s = src[e];
    int d = dst[e];
    const float4 v = *(const float4*)(h + (size_t)s * (C4 * 4) + c);
    float* p = agg + (size_t)d * (C4 * 4) + c;
    atomicAdd(p + 0, v.x);
    atomicAdd(p + 1, v.y);
    atomicAdd(p + 2, v.z);
    atomicAdd(p + 3, v.w);
}

// ---------------------------------------------------------------------------
// fused GEMM, M=256 fixed, full output width per block (64 rows/block).
// C[n,m] = act( bn( (A[n,:] (+AGG[n,:])) @ B[:,m] + bias[m] ) )
// Because one block owns its 64 rows entirely, C may alias A or AGG.
// 256 threads, 4x16 outputs/thread. A: [Nrows,K] rm, B: [K,256] rm.
// ---------------------------------------------------------------------------
template <bool ADD_AGG, bool DO_BN, bool DO_RELU>
__global__ __launch_bounds__(256) void mlp_gemm(
    const float* __restrict__ A, const float* __restrict__ AGG,
    const float* __restrict__ B, const float* __restrict__ bias,
    const float* __restrict__ bn_g, const float* __restrict__ bn_be,
    const float* __restrict__ bn_m, const float* __restrict__ bn_v,
    float* __restrict__ C, int Nrows, int K) {
    __shared__ float As[16][76];    // [k][row], stride 76: 16B-aligned rows, 2-way banks
    __shared__ float Bs[16][260];   // [k][col], stride 260: 16B-aligned rows

    const int tid  = threadIdx.x;
    const int row0 = blockIdx.x * 64;

    const int la_r = tid >> 2;          // 0..63 row within tile
    const int la_k = (tid & 3) << 2;    // 0,4,8,12
    const int wl   = tid & 63;          // lane
    const int wv   = tid >> 6;          // wave 0..3
    const int ty   = tid >> 4;          // 0..15 -> rows ty*4..+3
    const int tx   = tid & 15;          // 0..15 -> cols tx*4 + q*64

    float acc[4][16] = {};

    for (int kt = 0; kt < K; kt += 16) {
        // ---- load A tile (64 rows x 16 k), optional agg add ----
        {
            int ar = row0 + la_r;
            float4 av = make_float4(0.f, 0.f, 0.f, 0.f);
            if (ar < Nrows) {
                av = *(const float4*)(A + (size_t)ar * K + kt + la_k);
                if (ADD_AGG) {
                    const float4 gv = *(const float4*)(AGG + (size_t)ar * K + kt + la_k);
                    av.x += gv.x; av.y += gv.y; av.z += gv.z; av.w += gv.w;
                }
            }
            As[la_k + 0][la_r] = av.x;
            As[la_k + 1][la_r] = av.y;
            As[la_k + 2][la_r] = av.z;
            As[la_k + 3][la_r] = av.w;
        }
        // ---- load B tile (16 k x 256 cols): wave w loads rows 4w..4w+3 ----
#pragma unroll
        for (int r = 0; r < 4; ++r) {
            int bk = wv * 4 + r;
            const float4 bv = *(const float4*)(B + (size_t)(kt + bk) * 256 + wl * 4);
            *(float4*)&Bs[bk][wl * 4] = bv;
        }
        __syncthreads();

#pragma unroll
        for (int kk = 0; kk < 16; ++kk) {
            const float4 a = *(const float4*)&As[kk][ty * 4];
            const float av4[4] = {a.x, a.y, a.z, a.w};
#pragma unroll
            for (int q = 0; q < 4; ++q) {
                const float4 b = *(const float4*)&Bs[kk][tx * 4 + q * 64];
                const float bv4[4] = {b.x, b.y, b.z, b.w};
#pragma unroll
                for (int i = 0; i < 4; ++i)
#pragma unroll
                    for (int j = 0; j < 4; ++j)
                        acc[i][q * 4 + j] += av4[i] * bv4[j];
            }
        }
        __syncthreads();
    }

    // ---- epilogue: bias (+BN) (+ReLU), float4 stores; C may alias A/AGG ----
#pragma unroll
    for (int i = 0; i < 4; ++i) {
        int r = row0 + ty * 4 + i;
        if (r >= Nrows) continue;
#pragma unroll
        for (int q = 0; q < 4; ++q) {
            int c = tx * 4 + q * 64;
            float4 o;
            float* po = (float*)&o;
#pragma unroll
            for (int j = 0; j < 4; ++j) {
                int cc = c + j;
                float h = acc[i][q * 4 + j] + bias[cc];
                if (DO_BN) {
                    h = bn_g[cc] * (h - bn_m[cc]) * rsqrtf(bn_v[cc] + BN_EPS) + bn_be[cc];
                }
                if (DO_RELU) h = fmaxf(h, 0.f);
                po[j] = h;
            }
            *(float4*)(C + (size_t)r * 256 + c) = o;
        }
    }
}

// ---------------------------------------------------------------------------
// global add pool: pooled[batch[n]] += h[n], h is [N,256]
// ---------------------------------------------------------------------------
__global__ void pool_kernel(const float* __restrict__ h,
                            const int* __restrict__ batch,
                            float* __restrict__ pooled,
                            int total /* = N * 64 */) {
    int i = blockIdx.x * blockDim.x + threadIdx.x;
    if (i >= total) return;
    int n = i >> 6;
    int c = (i & 63) << 2;
    int g = batch[n];
    const float4 v = *(const float4*)(h + (size_t)n * 256 + c);
    float* p = pooled + (size_t)g * 256 + c;
    atomicAdd(p + 0, v.x);
    atomicAdd(p + 1, v.y);
    atomicAdd(p + 2, v.z);
    atomicAdd(p + 3, v.w);
}

// ---------------------------------------------------------------------------
// head: out[g] = relu(bn(pooled[g]@w0 + b0)) @ w1 + b1; one 128-thr block/graph
// ---------------------------------------------------------------------------
__global__ __launch_bounds__(128) void head_kernel(
    const float* __restrict__ pooled,
    const float* __restrict__ w0, const float* __restrict__ b0,
    const float* __restrict__ g, const float* __restrict__ be,
    const float* __restrict__ m, const float* __restrict__ v,
    const float* __restrict__ w1, const float* __restrict__ b1,
    float* __restrict__ out) {
    __shared__ float row[256];
    __shared__ float red[128];
    const int gid = blockIdx.x;
    const int j = threadIdx.x;  // 0..127

    row[j]       = pooled[(size_t)gid * 256 + j];
    row[j + 128] = pooled[(size_t)gid * 256 + 128 + j];
    __syncthreads();

    float acc = b0[j];
#pragma unroll 8
    for (int k = 0; k < 256; ++k) acc += row[k] * w0[k * 128 + j];

    float h = g[j] * (acc - m[j]) * rsqrtf(v[j] + BN_EPS) + be[j];
    h = fmaxf(h, 0.f) * w1[j];
    red[j] = h;
    __syncthreads();
    for (int s = 64; s > 0; s >>= 1) {
        if (j < s) red[j] += red[j + s];
        __syncthreads();
    }
    if (j == 0) out[gid] = red[0] + b1[0];
}

// ---------------------------------------------------------------------------
// launch
// ---------------------------------------------------------------------------
extern "C" void kernel_launch(void* const* d_in, const int* in_sizes, int n_in,
                              void* d_out, int out_size, void* d_ws, size_t ws_size,
                              hipStream_t stream) {
    const float* x    = (const float*)d_in[0];
    const int* eidx   = (const int*)d_in[1];
    const int* batch  = (const int*)d_in[2];

    const int N = in_sizes[0] / 128;
    const int E = in_sizes[1] / 2;
    const int G = out_size;

    const int* src = eidx;
    const int* dst = eidx + E;

    const float* cw1[3]; const float* cb1[3]; const float* cg[3]; const float* cbe[3];
    const float* cm[3];  const float* cv[3];  const float* cw2[3]; const float* cb2[3];
    for (int i = 0; i < 3; ++i) {
        int b = 3 + i * 8;
        cw1[i] = (const float*)d_in[b + 0];
        cb1[i] = (const float*)d_in[b + 1];
        cg[i]  = (const float*)d_in[b + 2];
        cbe[i] = (const float*)d_in[b + 3];
        cm[i]  = (const float*)d_in[b + 4];
        cv[i]  = (const float*)d_in[b + 5];
        cw2[i] = (const float*)d_in[b + 6];
        cb2[i] = (const float*)d_in[b + 7];
    }
    const float* l0_w  = (const float*)d_in[27];
    const float* l0_b  = (const float*)d_in[28];
    const float* l0_g  = (const float*)d_in[29];
    const float* l0_be = (const float*)d_in[30];
    const float* l0_m  = (const float*)d_in[31];
    const float* l0_v  = (const float*)d_in[32];
    const float* l1_w  = (const float*)d_in[33];
    const float* l1_b  = (const float*)d_in[34];

    float* outp = (float*)d_out;

    // workspace: two N x 256 fp32 buffers (pooled reuses U)
    const size_t BUF = (size_t)N * 256 * sizeof(float);
    if (ws_size < 2 * BUF) return;  // clean diagnostic failure instead of page fault
    char* ws = (char*)d_ws;
    float* U = (float*)(ws);
    float* V = (float*)(ws + BUF);

    const dim3 blk(256);
    const int nblk = (N + 63) / 64;

    // ---------------- layer 0 (128 -> 256) ----------------
    hipMemsetAsync(U, 0, (size_t)N * 128 * sizeof(float), stream);
    {
        int total = E * 32;  // C4 = 128/4
        scatter_add_kernel<32><<<(total + 255) / 256, blk, 0, stream>>>(x, src, dst, U, total);
    }
    mlp_gemm<true, true, true><<<nblk, blk, 0, stream>>>(
        x, U, cw1[0], cb1[0], cg[0], cbe[0], cm[0], cv[0], V, N, 128);
    mlp_gemm<false, false, true><<<nblk, blk, 0, stream>>>(
        V, nullptr, cw2[0], cb2[0], nullptr, nullptr, nullptr, nullptr, V, N, 256);

    // ---------------- layer 1 ----------------
    hipMemsetAsync(U, 0, BUF, stream);
    {
        int total = E * 64;
        scatter_add_kernel<64><<<(total + 255) / 256, blk, 0, stream>>>(V, src, dst, U, total);
    }
    mlp_gemm<true, true, true><<<nblk, blk, 0, stream>>>(
        V, U, cw1[1], cb1[1], cg[1], cbe[1], cm[1], cv[1], U, N, 256);
    mlp_gemm<false, false, true><<<nblk, blk, 0, stream>>>(
        U, nullptr, cw2[1], cb2[1], nullptr, nullptr, nullptr, nullptr, U, N, 256);

    // ---------------- layer 2 ----------------
    hipMemsetAsync(V, 0, BUF, stream);
    {
        int total = E * 64;
        scatter_add_kernel<64><<<(total + 255) / 256, blk, 0, stream>>>(U, src, dst, V, total);
    }
    mlp_gemm<true, true, true><<<nblk, blk, 0, stream>>>(
        U, V, cw1[2], cb1[2], cg[2], cbe[2], cm[2], cv[2], V, N, 256);
    mlp_gemm<false, false, true><<<nblk, blk, 0, stream>>>(
        V, nullptr, cw2[2], cb2[2], nullptr, nullptr, nullptr, nullptr, V, N, 256);

    // ---------------- pooling (pooled lives in U) ----------------
    float* pooled = U;
    hipMemsetAsync(pooled, 0, (size_t)G * 256 * sizeof(float), stream);
    {
        int total = N * 64;
        pool_kernel<<<(total + 255) / 256, blk, 0, stream>>>(V, batch, pooled, total);
    }

    // ---------------- head ----------------
    head_kernel<<<G, dim3(128), 0, stream>>>(pooled, l0_w, l0_b, l0_g, l0_be, l0_m, l0_v,
                                             l1_w, l1_b, outp);
}

// Round 3
// 1323.493 us; speedup vs baseline: 4.8230x; 4.8230x over previous
//
#include <hip/hip_runtime.h>
#include <hip/hip_bf16.h>

#define BN_EPS 1e-5f

// ===========================================================================
// CSR construction (per call; graph identical across the 3 layers)
// ===========================================================================
__global__ void hist_kernel(const int* __restrict__ dst, int* __restrict__ off, int E) {
    int e = blockIdx.x * blockDim.x + threadIdx.x;
    if (e < E) atomicAdd(&off[dst[e] + 1], 1);
}

// scan1: each 256-thread block inclusively scans 1024 elements in place,
// writes block total to sums[b]
__global__ __launch_bounds__(256) void scan1_kernel(int* __restrict__ data,
                                                    int* __restrict__ sums, int n) {
    __shared__ int sh[256];
    const int t = threadIdx.x;
    const int idx = blockIdx.x * 1024 + t * 4;
    int v[4];
    int s = 0;
#pragma unroll
    for (int j = 0; j < 4; ++j) {
        int x = (idx + j < n) ? data[idx + j] : 0;
        s += x;
        v[j] = s;  // inclusive within thread
    }
    sh[t] = s;
    __syncthreads();
    for (int o = 1; o < 256; o <<= 1) {
        int x = (t >= o) ? sh[t - o] : 0;
        __syncthreads();
        sh[t] += x;
        __syncthreads();
    }
    const int prev = sh[t] - s;  // exclusive prefix of earlier threads
#pragma unroll
    for (int j = 0; j < 4; ++j) {
        if (idx + j < n) data[idx + j] = v[j] + prev;
    }
    if (t == 255) sums[blockIdx.x] = sh[255];
}

// scan2: single block inclusive-scan of block sums (nb <= 256)
__global__ __launch_bounds__(256) void scan2_kernel(int* __restrict__ sums, int nb) {
    __shared__ int sh[256];
    const int t = threadIdx.x;
    sh[t] = (t < nb) ? sums[t] : 0;
    __syncthreads();
    for (int o = 1; o < 256; o <<= 1) {
        int x = (t >= o) ? sh[t - o] : 0;
        __syncthreads();
        sh[t] += x;
        __syncthreads();
    }
    if (t < nb) sums[t] = sh[t];
}

// scan3: add scanned block sums to following blocks
__global__ void scan3_kernel(int* __restrict__ data, const int* __restrict__ sums, int n) {
    int i = blockIdx.x * blockDim.x + threadIdx.x;
    if (i >= n) return;
    int b = i >> 10;
    if (b > 0) data[i] += sums[b - 1];
}

__global__ void copy_kernel(const int* __restrict__ a, int* __restrict__ b, int n) {
    int i = blockIdx.x * blockDim.x + threadIdx.x;
    if (i < n) b[i] = a[i];
}

__global__ void fill_kernel(const int* __restrict__ src, const int* __restrict__ dst,
                            int* __restrict__ cursor, int* __restrict__ sorted_src, int E) {
    int e = blockIdx.x * blockDim.x + threadIdx.x;
    if (e >= E) return;
    int p = atomicAdd(&cursor[dst[e]], 1);
    sorted_src[p] = src[e];
}

// ===========================================================================
// CSR aggregate: agg[n] = sum over incoming edges of h[src]; no atomics.
// C4 consecutive threads own one node's row (float4 chunks, coalesced).
// ===========================================================================
template <int C>
__global__ void aggregate_kernel(const float* __restrict__ h,
                                 const int* __restrict__ off,
                                 const int* __restrict__ sorted_src,
                                 float* __restrict__ agg, int N) {
    constexpr int C4 = C / 4;
    int t = blockIdx.x * blockDim.x + threadIdx.x;
    int n = t / C4;
    if (n >= N) return;
    int c = (t - n * C4) * 4;
    const int e0 = off[n], e1 = off[n + 1];
    float4 acc = make_float4(0.f, 0.f, 0.f, 0.f);
    for (int e = e0; e < e1; ++e) {
        const int s = sorted_src[e];
        const float4 v = *(const float4*)(h + (size_t)s * C + c);
        acc.x += v.x; acc.y += v.y; acc.z += v.z; acc.w += v.w;
    }
    *(float4*)(agg + (size_t)n * C + c) = acc;
}

// ===========================================================================
// fallback scatter-add (used only if workspace too small for CSR)
// ===========================================================================
template <int C4>
__global__ void scatter_add_kernel(const float* __restrict__ h,
                                   const int* __restrict__ src,
                                   const int* __restrict__ dst,
                                   float* __restrict__ agg,
                                   int total) {
    int i = blockIdx.x * blockDim.x + threadIdx.x;
    if (i >= total) return;
    int e = i / C4;
    int c = (i - e * C4) * 4;
    int s = src[e];
    int d = dst[e];
    const float4 v = *(const float4*)(h + (size_t)s * (C4 * 4) + c);
    float* p = agg + (size_t)d * (C4 * 4) + c;
    atomicAdd(p + 0, v.x);
    atomicAdd(p + 1, v.y);
    atomicAdd(p + 2, v.z);
    atomicAdd(p + 3, v.w);
}

// ===========================================================================
// fused GEMM, M=256 fixed, full output width per block (64 rows/block).
// C[n,m] = act( bn( (A[n,:] (+AGG[n,:])) @ B[:,m] + bias[m] ) )
// One block owns its 64 rows entirely -> C may alias A or AGG.
// ===========================================================================
template <bool ADD_AGG, bool DO_BN, bool DO_RELU>
__global__ __launch_bounds__(256) void mlp_gemm(
    const float* __restrict__ A, const float* __restrict__ AGG,
    const float* __restrict__ B, const float* __restrict__ bias,
    const float* __restrict__ bn_g, const float* __restrict__ bn_be,
    const float* __restrict__ bn_m, const float* __restrict__ bn_v,
    float* __restrict__ C, int Nrows, int K) {
    __shared__ float As[16][76];
    __shared__ float Bs[16][260];

    const int tid  = threadIdx.x;
    const int row0 = blockIdx.x * 64;

    const int la_r = tid >> 2;
    const int la_k = (tid & 3) << 2;
    const int wl   = tid & 63;
    const int wv   = tid >> 6;
    const int ty   = tid >> 4;
    const int tx   = tid & 15;

    float acc[4][16] = {};

    for (int kt = 0; kt < K; kt += 16) {
        {
            int ar = row0 + la_r;
            float4 av = make_float4(0.f, 0.f, 0.f, 0.f);
            if (ar < Nrows) {
                av = *(const float4*)(A + (size_t)ar * K + kt + la_k);
                if (ADD_AGG) {
                    const float4 gv = *(const float4*)(AGG + (size_t)ar * K + kt + la_k);
                    av.x += gv.x; av.y += gv.y; av.z += gv.z; av.w += gv.w;
                }
            }
            As[la_k + 0][la_r] = av.x;
            As[la_k + 1][la_r] = av.y;
            As[la_k + 2][la_r] = av.z;
            As[la_k + 3][la_r] = av.w;
        }
#pragma unroll
        for (int r = 0; r < 4; ++r) {
            int bk = wv * 4 + r;
            const float4 bv = *(const float4*)(B + (size_t)(kt + bk) * 256 + wl * 4);
            *(float4*)&Bs[bk][wl * 4] = bv;
        }
        __syncthreads();

#pragma unroll
        for (int kk = 0; kk < 16; ++kk) {
            const float4 a = *(const float4*)&As[kk][ty * 4];
            const float av4[4] = {a.x, a.y, a.z, a.w};
#pragma unroll
            for (int q = 0; q < 4; ++q) {
                const float4 b = *(const float4*)&Bs[kk][tx * 4 + q * 64];
                const float bv4[4] = {b.x, b.y, b.z, b.w};
#pragma unroll
                for (int i = 0; i < 4; ++i)
#pragma unroll
                    for (int j = 0; j < 4; ++j)
                        acc[i][q * 4 + j] += av4[i] * bv4[j];
            }
        }
        __syncthreads();
    }

#pragma unroll
    for (int i = 0; i < 4; ++i) {
        int r = row0 + ty * 4 + i;
        if (r >= Nrows) continue;
#pragma unroll
        for (int q = 0; q < 4; ++q) {
            int c = tx * 4 + q * 64;
            float4 o;
            float* po = (float*)&o;
#pragma unroll
            for (int j = 0; j < 4; ++j) {
                int cc = c + j;
                float h = acc[i][q * 4 + j] + bias[cc];
                if (DO_BN) {
                    h = bn_g[cc] * (h - bn_m[cc]) * rsqrtf(bn_v[cc] + BN_EPS) + bn_be[cc];
                }
                if (DO_RELU) h = fmaxf(h, 0.f);
                po[j] = h;
            }
            *(float4*)(C + (size_t)r * 256 + c) = o;
        }
    }
}

// ===========================================================================
// segmented pool over sorted batch: one block per graph, no atomics
// ===========================================================================
__device__ __forceinline__ int lower_bound_dev(const int* __restrict__ a, int n, int key) {
    int lo = 0, hi = n;
    while (lo < hi) {
        int mid = (lo + hi) >> 1;
        if (a[mid] < key) lo = mid + 1; else hi = mid;
    }
    return lo;
}

__global__ __launch_bounds__(256) void pool_seg_kernel(const float* __restrict__ h,
                                                       const int* __restrict__ batch,
                                                       float* __restrict__ pooled,
                                                       int N) {
    __shared__ int seg[2];
    const int g = blockIdx.x;
    if (threadIdx.x == 0) seg[0] = lower_bound_dev(batch, N, g);
    if (threadIdx.x == 1) seg[1] = lower_bound_dev(batch, N, g + 1);
    __syncthreads();
    const int c = threadIdx.x;
    float acc = 0.f;
    for (int n = seg[0]; n < seg[1]; ++n) acc += h[(size_t)n * 256 + c];
    pooled[(size_t)g * 256 + c] = acc;
}

// ===========================================================================
// head: out[g] = relu(bn(pooled[g]@w0 + b0)) @ w1 + b1
// ===========================================================================
__global__ __launch_bounds__(128) void head_kernel(
    const float* __restrict__ pooled,
    const float* __restrict__ w0, const float* __restrict__ b0,
    const float* __restrict__ g, const float* __restrict__ be,
    const float* __restrict__ m, const float* __restrict__ v,
    const float* __restrict__ w1, const float* __restrict__ b1,
    float* __restrict__ out) {
    __shared__ float row[256];
    __shared__ float red[128];
    const int gid = blockIdx.x;
    const int j = threadIdx.x;

    row[j]       = pooled[(size_t)gid * 256 + j];
    row[j + 128] = pooled[(size_t)gid * 256 + 128 + j];
    __syncthreads();

    float acc = b0[j];
#pragma unroll 8
    for (int k = 0; k < 256; ++k) acc += row[k] * w0[k * 128 + j];

    float h = g[j] * (acc - m[j]) * rsqrtf(v[j] + BN_EPS) + be[j];
    h = fmaxf(h, 0.f) * w1[j];
    red[j] = h;
    __syncthreads();
    for (int s = 64; s > 0; s >>= 1) {
        if (j < s) red[j] += red[j + s];
        __syncthreads();
    }
    if (j == 0) out[gid] = red[0] + b1[0];
}

// ===========================================================================
// launch
// ===========================================================================
extern "C" void kernel_launch(void* const* d_in, const int* in_sizes, int n_in,
                              void* d_out, int out_size, void* d_ws, size_t ws_size,
                              hipStream_t stream) {
    const float* x    = (const float*)d_in[0];
    const int* eidx   = (const int*)d_in[1];
    const int* batch  = (const int*)d_in[2];

    const int N = in_sizes[0] / 128;
    const int E = in_sizes[1] / 2;
    const int G = out_size;

    const int* src = eidx;
    const int* dst = eidx + E;

    const float* cw1[3]; const float* cb1[3]; const float* cg[3]; const float* cbe[3];
    const float* cm[3];  const float* cv[3];  const float* cw2[3]; const float* cb2[3];
    for (int i = 0; i < 3; ++i) {
        int b = 3 + i * 8;
        cw1[i] = (const float*)d_in[b + 0];
        cb1[i] = (const float*)d_in[b + 1];
        cg[i]  = (const float*)d_in[b + 2];
        cbe[i] = (const float*)d_in[b + 3];
        cm[i]  = (const float*)d_in[b + 4];
        cv[i]  = (const float*)d_in[b + 5];
        cw2[i] = (const float*)d_in[b + 6];
        cb2[i] = (const float*)d_in[b + 7];
    }
    const float* l0_w  = (const float*)d_in[27];
    const float* l0_b  = (const float*)d_in[28];
    const float* l0_g  = (const float*)d_in[29];
    const float* l0_be = (const float*)d_in[30];
    const float* l0_m  = (const float*)d_in[31];
    const float* l0_v  = (const float*)d_in[32];
    const float* l1_w  = (const float*)d_in[33];
    const float* l1_b  = (const float*)d_in[34];

    float* outp = (float*)d_out;

    // ---- workspace layout ----
    const size_t BUF = (size_t)N * 256 * sizeof(float);
    if (ws_size < 2 * BUF) return;
    char* ws = (char*)d_ws;
    float* U = (float*)(ws);
    float* V = (float*)(ws + BUF);

    int* csr_off    = (int*)(ws + 2 * BUF);       // N+1
    int* cursor     = csr_off + (N + 1);          // N
    int* sorted_src = cursor + N;                 // E
    int* sums       = sorted_src + E;             // 256
    const size_t NEED = 2 * BUF + ((size_t)(N + 1) + N + E + 256) * sizeof(int);
    const bool use_csr = (ws_size >= NEED);

    const dim3 blk(256);
    const int nblk = (N + 63) / 64;

    // ---- build CSR (once; graph shared by all 3 layers) ----
    if (use_csr) {
        const int n_off = N + 1;
        hipMemsetAsync(csr_off, 0, (size_t)n_off * sizeof(int), stream);
        hist_kernel<<<(E + 255) / 256, blk, 0, stream>>>(dst, csr_off, E);
        const int nb = (n_off + 1023) / 1024;  // <= 256 for N <= 262k
        scan1_kernel<<<nb, blk, 0, stream>>>(csr_off, sums, n_off);
        scan2_kernel<<<1, blk, 0, stream>>>(sums, nb);
        scan3_kernel<<<(n_off + 255) / 256, blk, 0, stream>>>(csr_off, sums, n_off);
        copy_kernel<<<(N + 255) / 256, blk, 0, stream>>>(csr_off, cursor, N);
        fill_kernel<<<(E + 255) / 256, blk, 0, stream>>>(src, dst, cursor, sorted_src, E);
    }

    // helper lambdas for the two aggregate paths
    auto agg128 = [&](const float* h, float* agg) {
        if (use_csr) {
            int total = N * 32;
            aggregate_kernel<128><<<(total + 255) / 256, blk, 0, stream>>>(h, csr_off, sorted_src, agg, N);
        } else {
            hipMemsetAsync(agg, 0, (size_t)N * 128 * sizeof(float), stream);
            int total = E * 32;
            scatter_add_kernel<32><<<(total + 255) / 256, blk, 0, stream>>>(h, src, dst, agg, total);
        }
    };
    auto agg256 = [&](const float* h, float* agg) {
        if (use_csr) {
            int total = N * 64;
            aggregate_kernel<256><<<(total + 255) / 256, blk, 0, stream>>>(h, csr_off, sorted_src, agg, N);
        } else {
            hipMemsetAsync(agg, 0, BUF, stream);
            int total = E * 64;
            scatter_add_kernel<64><<<(total + 255) / 256, blk, 0, stream>>>(h, src, dst, agg, total);
        }
    };

    // ---------------- layer 0 (128 -> 256) ----------------
    agg128(x, U);
    mlp_gemm<true, true, true><<<nblk, blk, 0, stream>>>(
        x, U, cw1[0], cb1[0], cg[0], cbe[0], cm[0], cv[0], V, N, 128);
    mlp_gemm<false, false, true><<<nblk, blk, 0, stream>>>(
        V, nullptr, cw2[0], cb2[0], nullptr, nullptr, nullptr, nullptr, V, N, 256);

    // ---------------- layer 1 ----------------
    agg256(V, U);
    mlp_gemm<true, true, true><<<nblk, blk, 0, stream>>>(
        V, U, cw1[1], cb1[1], cg[1], cbe[1], cm[1], cv[1], U, N, 256);
    mlp_gemm<false, false, true><<<nblk, blk, 0, stream>>>(
        U, nullptr, cw2[1], cb2[1], nullptr, nullptr, nullptr, nullptr, U, N, 256);

    // ---------------- layer 2 ----------------
    agg256(U, V);
    mlp_gemm<true, true, true><<<nblk, blk, 0, stream>>>(
        U, V, cw1[2], cb1[2], cg[2], cbe[2], cm[2], cv[2], V, N, 256);
    mlp_gemm<false, false, true><<<nblk, blk, 0, stream>>>(
        V, nullptr, cw2[2], cb2[2], nullptr, nullptr, nullptr, nullptr, V, N, 256);

    // ---------------- pooling (pooled lives in U) ----------------
    float* pooled = U;
    pool_seg_kernel<<<G, blk, 0, stream>>>(V, batch, pooled, N);

    // ---------------- head ----------------
    head_kernel<<<G, dim3(128), 0, stream>>>(pooled, l0_w, l0_b, l0_g, l0_be, l0_m, l0_v,
                                             l1_w, l1_b, outp);
}

// Round 4
// 505.844 us; speedup vs baseline: 12.6188x; 2.6164x over previous
//
#include <hip/hip_runtime.h>
#include <hip/hip_bf16.h>

#define BN_EPS 1e-5f

typedef __attribute__((ext_vector_type(8))) short short8;
typedef __attribute__((ext_vector_type(4))) float f32x4;

__device__ __forceinline__ void gll16(const void* g, void* l) {
    __builtin_amdgcn_global_load_lds(
        (const __attribute__((address_space(1))) unsigned int*)g,
        (__attribute__((address_space(3))) unsigned int*)l, 16, 0, 0);
}

// ===========================================================================
// CSR construction (graph identical across the 3 layers)
// ===========================================================================
__global__ void hist_kernel(const int* __restrict__ dst, int* __restrict__ off, int E) {
    int e = blockIdx.x * blockDim.x + threadIdx.x;
    if (e < E) atomicAdd(&off[dst[e] + 1], 1);
}

__global__ __launch_bounds__(256) void scan1_kernel(int* __restrict__ data,
                                                    int* __restrict__ sums, int n) {
    __shared__ int sh[256];
    const int t = threadIdx.x;
    const int idx = blockIdx.x * 1024 + t * 4;
    int v[4];
    int s = 0;
#pragma unroll
    for (int j = 0; j < 4; ++j) {
        int x = (idx + j < n) ? data[idx + j] : 0;
        s += x;
        v[j] = s;
    }
    sh[t] = s;
    __syncthreads();
    for (int o = 1; o < 256; o <<= 1) {
        int x = (t >= o) ? sh[t - o] : 0;
        __syncthreads();
        sh[t] += x;
        __syncthreads();
    }
    const int prev = sh[t] - s;
#pragma unroll
    for (int j = 0; j < 4; ++j) {
        if (idx + j < n) data[idx + j] = v[j] + prev;
    }
    if (t == 255) sums[blockIdx.x] = sh[255];
}

__global__ __launch_bounds__(256) void scan2_kernel(int* __restrict__ sums, int nb) {
    __shared__ int sh[256];
    const int t = threadIdx.x;
    sh[t] = (t < nb) ? sums[t] : 0;
    __syncthreads();
    for (int o = 1; o < 256; o <<= 1) {
        int x = (t >= o) ? sh[t - o] : 0;
        __syncthreads();
        sh[t] += x;
        __syncthreads();
    }
    if (t < nb) sums[t] = sh[t];
}

__global__ void scan3_kernel(int* __restrict__ data, const int* __restrict__ sums, int n) {
    int i = blockIdx.x * blockDim.x + threadIdx.x;
    if (i >= n) return;
    int b = i >> 10;
    if (b > 0) data[i] += sums[b - 1];
}

__global__ void copy_kernel(const int* __restrict__ a, int* __restrict__ b, int n) {
    int i = blockIdx.x * blockDim.x + threadIdx.x;
    if (i < n) b[i] = a[i];
}

__global__ void fill_kernel(const int* __restrict__ src, const int* __restrict__ dst,
                            int* __restrict__ cursor, int* __restrict__ sorted_src, int E) {
    int e = blockIdx.x * blockDim.x + threadIdx.x;
    if (e >= E) return;
    int p = atomicAdd(&cursor[dst[e]], 1);
    sorted_src[p] = src[e];
}

// ===========================================================================
// prep: x -> bf16 (padded rows zeroed)
// ===========================================================================
__global__ void cvt_x_kernel(const float* __restrict__ x, __hip_bfloat16* __restrict__ xb,
                             int N, int total /* Npad*128 */) {
    int i = blockIdx.x * blockDim.x + threadIdx.x;
    if (i >= total) return;
    int n = i >> 7;
    float v = (n < N) ? x[i] : 0.f;
    xb[i] = __float2bfloat16(v);
}

// weights: Wt[m*K + k] = bf16(W[k*M + m])
__global__ void wt_kernel(const float* __restrict__ W, __hip_bfloat16* __restrict__ Wt,
                          int K, int M) {
    int i = blockIdx.x * blockDim.x + threadIdx.x;
    if (i >= M * K) return;
    int m = i / K, k = i - m * K;
    Wt[i] = __float2bfloat16(W[k * M + m]);
}

// fold bias+BN into scale/shift: out = acc*s + t
__global__ void bnprep_kernel(const float* __restrict__ g, const float* __restrict__ be,
                              const float* __restrict__ m, const float* __restrict__ v,
                              const float* __restrict__ b1,
                              float* __restrict__ sc, float* __restrict__ sh) {
    int c = threadIdx.x;
    float r = rsqrtf(v[c] + BN_EPS);
    float s = g[c] * r;
    sc[c] = s;
    sh[c] = (b1[c] - m[c]) * s + be[c];
}

__global__ void biasprep_kernel(const float* __restrict__ b,
                                float* __restrict__ sc, float* __restrict__ sh) {
    int c = threadIdx.x;
    sc[c] = 1.f;
    sh[c] = b[c];
}

// ===========================================================================
// fused aggregate: out[n] = h[n] + sum_{e in CSR(n)} h[src[e]]  (bf16 in/out)
// C/8 lanes per node, 16B chunks.
// ===========================================================================
template <int C>
__global__ __launch_bounds__(256) void agg_fused(const __hip_bfloat16* __restrict__ h,
                                                 const int* __restrict__ off,
                                                 const int* __restrict__ ssrc,
                                                 __hip_bfloat16* __restrict__ out, int N) {
    constexpr int L = C / 8;
    int t = blockIdx.x * blockDim.x + threadIdx.x;
    int n = t / L;
    if (n >= N) return;
    int c8 = t - n * L;
    const uint4* hp = (const uint4*)h;

    float acc[8];
    uint4 sv = hp[(size_t)n * L + c8];
    {
        const unsigned u[4] = {sv.x, sv.y, sv.z, sv.w};
#pragma unroll
        for (int j = 0; j < 4; ++j) {
            unsigned lo = u[j] << 16, hi = u[j] & 0xffff0000u;
            acc[2 * j]     = __uint_as_float(lo);
            acc[2 * j + 1] = __uint_as_float(hi);
        }
    }
    const int e0 = off[n], e1 = off[n + 1];
    for (int e = e0; e < e1; ++e) {
        int s = ssrc[e];
        uint4 vv = hp[(size_t)s * L + c8];
        const unsigned u[4] = {vv.x, vv.y, vv.z, vv.w};
#pragma unroll
        for (int j = 0; j < 4; ++j) {
            acc[2 * j]     += __uint_as_float(u[j] << 16);
            acc[2 * j + 1] += __uint_as_float(u[j] & 0xffff0000u);
        }
    }
    // pack back to bf16
    unsigned o[4];
#pragma unroll
    for (int j = 0; j < 4; ++j) {
        __hip_bfloat16 a = __float2bfloat16(acc[2 * j]);
        __hip_bfloat16 b = __float2bfloat16(acc[2 * j + 1]);
        unsigned short ua = *(unsigned short*)&a, ub = *(unsigned short*)&b;
        o[j] = (unsigned)ua | ((unsigned)ub << 16);
    }
    uint4 ov = make_uint4(o[0], o[1], o[2], o[3]);
    ((uint4*)out)[(size_t)n * L + c8] = ov;
}

// ===========================================================================
// MFMA GEMM: C[Npad,256] = relu( (A[Npad,K] @ W[K,256]) * sc + sh )
// Wt is W transposed: [256][K] bf16. Block 128x128, 4 waves (2x2), 64x64/wave.
// BK=64, global_load_lds staging with pre-swizzled source (T2/m173).
// ===========================================================================
template <int K>
__global__ __launch_bounds__(256) void gemm_mfma(
    const __hip_bfloat16* __restrict__ A,
    const __hip_bfloat16* __restrict__ Wt,
    const float* __restrict__ sc, const float* __restrict__ sh,
    __hip_bfloat16* __restrict__ C) {
    __shared__ short ldsA[128 * 64];  // [128 rows][128 bytes], XOR-swizzled content
    __shared__ short ldsB[128 * 64];

    const int tid = threadIdx.x;
    const int l = tid & 63;
    const int w = tid >> 6;
    const int wr = w >> 1, wc = w & 1;
    const int rb = blockIdx.x >> 1;
    const int cb = blockIdx.x & 1;
    const int row0 = rb * 128;
    const int col0 = cb * 128;

    f32x4 acc[4][4] = {};

    // staging: wave w stages rows w*32..+31; instr i covers 8 rows; lane l ->
    // row += l>>3, byte slot (l&7)*16, source pre-XORed so LDS holds swizzled tile
    const int swz_st = ((l & 7) * 16) ^ ((l >> 3) << 4);
    const char* Ab = (const char*)A;
    const char* Bb = (const char*)Wt;

    // frag-read constants
    const int fr_row = l & 15;
    const int fr_sl = (l >> 4) * 16;
    const int fr_x = (l & 7) << 4;

    for (int kt = 0; kt < K; kt += 64) {
#pragma unroll
        for (int i = 0; i < 4; ++i) {
            const int rr = w * 32 + i * 8 + (l >> 3);
            gll16(Ab + (size_t)(row0 + rr) * (K * 2) + kt * 2 + swz_st,
                  (char*)ldsA + (w * 32 + i * 8) * 128);
            gll16(Bb + (size_t)(col0 + rr) * (K * 2) + kt * 2 + swz_st,
                  (char*)ldsB + (w * 32 + i * 8) * 128);
        }
        asm volatile("s_waitcnt vmcnt(0)" ::: "memory");
        __syncthreads();

#pragma unroll
        for (int k0 = 0; k0 < 2; ++k0) {
            short8 af[4], bf[4];
            const int byt = (k0 * 64 + fr_sl) ^ fr_x;
#pragma unroll
            for (int mi = 0; mi < 4; ++mi) {
                int row = wr * 64 + mi * 16 + fr_row;
                af[mi] = *(const short8*)((const char*)ldsA + row * 128 + byt);
            }
#pragma unroll
            for (int ni = 0; ni < 4; ++ni) {
                int col = wc * 64 + ni * 16 + fr_row;
                bf[ni] = *(const short8*)((const char*)ldsB + col * 128 + byt);
            }
#pragma unroll
            for (int mi = 0; mi < 4; ++mi)
#pragma unroll
                for (int ni = 0; ni < 4; ++ni)
                    acc[mi][ni] = __builtin_amdgcn_mfma_f32_16x16x32_bf16(
                        af[mi], bf[ni], acc[mi][ni], 0, 0, 0);
        }
        __syncthreads();
    }

    // epilogue: C/D layout col=lane&15, row=(lane>>4)*4+reg (m89-verified)
    const int lr = l >> 4;
    const int lc = l & 15;
#pragma unroll
    for (int ni = 0; ni < 4; ++ni) {
        const int col = col0 + wc * 64 + ni * 16 + lc;
        const float s = sc[col], t = sh[col];
#pragma unroll
        for (int mi = 0; mi < 4; ++mi) {
            const int grow = row0 + wr * 64 + mi * 16 + lr * 4;
#pragma unroll
            for (int r = 0; r < 4; ++r) {
                float vv = acc[mi][ni][r] * s + t;
                vv = fmaxf(vv, 0.f);
                C[(size_t)(grow + r) * 256 + col] = __float2bfloat16(vv);
            }
        }
    }
}

// ===========================================================================
// segmented pool (bf16 in, fp32 out), one block per graph
// ===========================================================================
__device__ __forceinline__ int lower_bound_dev(const int* __restrict__ a, int n, int key) {
    int lo = 0, hi = n;
    while (lo < hi) {
        int mid = (lo + hi) >> 1;
        if (a[mid] < key) lo = mid + 1; else hi = mid;
    }
    return lo;
}

__global__ __launch_bounds__(256) void pool_seg_kernel(const __hip_bfloat16* __restrict__ h,
                                                       const int* __restrict__ batch,
                                                       float* __restrict__ pooled, int N) {
    __shared__ int seg[2];
    const int g = blockIdx.x;
    if (threadIdx.x == 0) seg[0] = lower_bound_dev(batch, N, g);
    if (threadIdx.x == 1) seg[1] = lower_bound_dev(batch, N, g + 1);
    __syncthreads();
    const int c = threadIdx.x;
    float acc = 0.f;
    for (int n = seg[0]; n < seg[1]; ++n) acc += __bfloat162float(h[(size_t)n * 256 + c]);
    pooled[(size_t)g * 256 + c] = acc;
}

// ===========================================================================
// head: out[g] = relu(bn(pooled[g]@w0 + b0)) @ w1 + b1
// ===========================================================================
__global__ __launch_bounds__(128) void head_kernel(
    const float* __restrict__ pooled,
    const float* __restrict__ w0, const float* __restrict__ b0,
    const float* __restrict__ g, const float* __restrict__ be,
    const float* __restrict__ m, const float* __restrict__ v,
    const float* __restrict__ w1, const float* __restrict__ b1,
    float* __restrict__ out) {
    __shared__ float row[256];
    __shared__ float red[128];
    const int gid = blockIdx.x;
    const int j = threadIdx.x;

    row[j]       = pooled[(size_t)gid * 256 + j];
    row[j + 128] = pooled[(size_t)gid * 256 + 128 + j];
    __syncthreads();

    float acc = b0[j];
#pragma unroll 8
    for (int k = 0; k < 256; ++k) acc += row[k] * w0[k * 128 + j];

    float h = g[j] * (acc - m[j]) * rsqrtf(v[j] + BN_EPS) + be[j];
    h = fmaxf(h, 0.f) * w1[j];
    red[j] = h;
    __syncthreads();
    for (int s = 64; s > 0; s >>= 1) {
        if (j < s) red[j] += red[j + s];
        __syncthreads();
    }
    if (j == 0) out[gid] = red[0] + b1[0];
}

// ===========================================================================
// launch
// ===========================================================================
extern "C" void kernel_launch(void* const* d_in, const int* in_sizes, int n_in,
                              void* d_out, int out_size, void* d_ws, size_t ws_size,
                              hipStream_t stream) {
    const float* x    = (const float*)d_in[0];
    const int* eidx   = (const int*)d_in[1];
    const int* batch  = (const int*)d_in[2];

    const int N = in_sizes[0] / 128;
    const int E = in_sizes[1] / 2;
    const int G = out_size;

    const int* src = eidx;
    const int* dst = eidx + E;

    const float* cw1[3]; const float* cb1[3]; const float* cg[3]; const float* cbe[3];
    const float* cm[3];  const float* cv[3];  const float* cw2[3]; const float* cb2[3];
    for (int i = 0; i < 3; ++i) {
        int b = 3 + i * 8;
        cw1[i] = (const float*)d_in[b + 0];
        cb1[i] = (const float*)d_in[b + 1];
        cg[i]  = (const float*)d_in[b + 2];
        cbe[i] = (const float*)d_in[b + 3];
        cm[i]  = (const float*)d_in[b + 4];
        cv[i]  = (const float*)d_in[b + 5];
        cw2[i] = (const float*)d_in[b + 6];
        cb2[i] = (const float*)d_in[b + 7];
    }
    const float* l0_w  = (const float*)d_in[27];
    const float* l0_b  = (const float*)d_in[28];
    const float* l0_g  = (const float*)d_in[29];
    const float* l0_be = (const float*)d_in[30];
    const float* l0_m  = (const float*)d_in[31];
    const float* l0_v  = (const float*)d_in[32];
    const float* l1_w  = (const float*)d_in[33];
    const float* l1_b  = (const float*)d_in[34];

    float* outp = (float*)d_out;

    // ---- workspace layout ----
    const int nrb  = (N + 127) / 128;
    const int Npad = nrb * 128;
    const size_t SB = (size_t)Npad * 256 * 2;   // bf16 [Npad][256]
    const size_t XB = (size_t)Npad * 128 * 2;   // bf16 [Npad][128]
    const size_t PB = (size_t)G * 256 * 4;
    const size_t WTB = (size_t)256 * 256 * 2;   // one transposed weight slot
    const size_t SSB = (size_t)256 * 4;         // one scale or shift array

    char* ws = (char*)d_ws;
    size_t o = 0;
    __hip_bfloat16* B1 = (__hip_bfloat16*)(ws + o); o += SB;
    __hip_bfloat16* B2 = (__hip_bfloat16*)(ws + o); o += SB;
    __hip_bfloat16* B3 = (__hip_bfloat16*)(ws + o); o += SB;
    __hip_bfloat16* xb = (__hip_bfloat16*)(ws + o); o += XB;
    float* pooled      = (float*)(ws + o);       o += PB;
    __hip_bfloat16* wt[6];
    for (int i = 0; i < 6; ++i) { wt[i] = (__hip_bfloat16*)(ws + o); o += WTB; }
    float* scv[6]; float* shv[6];
    for (int i = 0; i < 6; ++i) {
        scv[i] = (float*)(ws + o); o += SSB;
        shv[i] = (float*)(ws + o); o += SSB;
    }
    int* csr_off    = (int*)(ws + o); o += (size_t)(N + 1) * 4;
    int* cursor     = (int*)(ws + o); o += (size_t)N * 4;
    int* sorted_src = (int*)(ws + o); o += (size_t)E * 4;
    int* sums       = (int*)(ws + o); o += 256 * 4;
    if (ws_size < o) return;  // clean failure instead of page fault

    const dim3 blk(256);

    // ---- prep: conversions, weight transposes, BN folds ----
    {
        int total = Npad * 128;
        cvt_x_kernel<<<(total + 255) / 256, blk, 0, stream>>>(x, xb, N, total);
    }
    // weights: order w1_0(K=128), w2_0, w1_1, w2_1, w1_2, w2_2
    wt_kernel<<<(256 * 128 + 255) / 256, blk, 0, stream>>>(cw1[0], wt[0], 128, 256);
    wt_kernel<<<(256 * 256 + 255) / 256, blk, 0, stream>>>(cw2[0], wt[1], 256, 256);
    wt_kernel<<<(256 * 256 + 255) / 256, blk, 0, stream>>>(cw1[1], wt[2], 256, 256);
    wt_kernel<<<(256 * 256 + 255) / 256, blk, 0, stream>>>(cw2[1], wt[3], 256, 256);
    wt_kernel<<<(256 * 256 + 255) / 256, blk, 0, stream>>>(cw1[2], wt[4], 256, 256);
    wt_kernel<<<(256 * 256 + 255) / 256, blk, 0, stream>>>(cw2[2], wt[5], 256, 256);
    for (int i = 0; i < 3; ++i) {
        bnprep_kernel<<<1, blk, 0, stream>>>(cg[i], cbe[i], cm[i], cv[i], cb1[i],
                                             scv[2 * i], shv[2 * i]);
        biasprep_kernel<<<1, blk, 0, stream>>>(cb2[i], scv[2 * i + 1], shv[2 * i + 1]);
    }

    // ---- CSR build ----
    {
        const int n_off = N + 1;
        hipMemsetAsync(csr_off, 0, (size_t)n_off * sizeof(int), stream);
        hist_kernel<<<(E + 255) / 256, blk, 0, stream>>>(dst, csr_off, E);
        const int nb = (n_off + 1023) / 1024;
        scan1_kernel<<<nb, blk, 0, stream>>>(csr_off, sums, n_off);
        scan2_kernel<<<1, blk, 0, stream>>>(sums, nb);
        scan3_kernel<<<(n_off + 255) / 256, blk, 0, stream>>>(csr_off, sums, n_off);
        copy_kernel<<<(N + 255) / 256, blk, 0, stream>>>(csr_off, cursor, N);
        fill_kernel<<<(E + 255) / 256, blk, 0, stream>>>(src, dst, cursor, sorted_src, E);
    }

    const int gemm_grid = nrb * 2;

    // ---------------- layer 0 (128 -> 256) ----------------
    {
        int total = N * 16;  // L = 128/8
        agg_fused<128><<<(total + 255) / 256, blk, 0, stream>>>(xb, csr_off, sorted_src,
                                                                (__hip_bfloat16*)B1, N);
    }
    gemm_mfma<128><<<gemm_grid, blk, 0, stream>>>(B1, wt[0], scv[0], shv[0], B2);
    gemm_mfma<256><<<gemm_grid, blk, 0, stream>>>(B2, wt[1], scv[1], shv[1], B3);

    // ---------------- layer 1 ----------------
    {
        int total = N * 32;
        agg_fused<256><<<(total + 255) / 256, blk, 0, stream>>>(B3, csr_off, sorted_src, B1, N);
    }
    gemm_mfma<256><<<gemm_grid, blk, 0, stream>>>(B1, wt[2], scv[2], shv[2], B2);
    gemm_mfma<256><<<gemm_grid, blk, 0, stream>>>(B2, wt[3], scv[3], shv[3], B3);

    // ---------------- layer 2 ----------------
    {
        int total = N * 32;
        agg_fused<256><<<(total + 255) / 256, blk, 0, stream>>>(B3, csr_off, sorted_src, B1, N);
    }
    gemm_mfma<256><<<gemm_grid, blk, 0, stream>>>(B1, wt[4], scv[4], shv[4], B2);
    gemm_mfma<256><<<gemm_grid, blk, 0, stream>>>(B2, wt[5], scv[5], shv[5], B3);

    // ---------------- pooling + head ----------------
    pool_seg_kernel<<<G, blk, 0, stream>>>(B3, batch, pooled, N);
    head_kernel<<<G, dim3(128), 0, stream>>>(pooled, l0_w, l0_b, l0_g, l0_be, l0_m, l0_v,
                                             l1_w, l1_b, outp);
}

// Round 5
// 460.085 us; speedup vs baseline: 13.8738x; 1.0995x over previous
//
#include <hip/hip_runtime.h>
#include <hip/hip_bf16.h>

#define BN_EPS 1e-5f

typedef __attribute__((ext_vector_type(8))) short short8;
typedef __attribute__((ext_vector_type(4))) float f32x4;

__device__ __forceinline__ void gll16(const void* g, void* l) {
    __builtin_amdgcn_global_load_lds(
        (const __attribute__((address_space(1))) unsigned int*)g,
        (__attribute__((address_space(3))) unsigned int*)l, 16, 0, 0);
}

// ===========================================================================
// CSR construction (graph identical across the 3 layers)
// ===========================================================================
__global__ void hist_kernel(const int* __restrict__ dst, int* __restrict__ off, int E) {
    int e = blockIdx.x * blockDim.x + threadIdx.x;
    if (e < E) atomicAdd(&off[dst[e] + 1], 1);
}

__global__ __launch_bounds__(256) void scan1_kernel(int* __restrict__ data,
                                                    int* __restrict__ sums, int n) {
    __shared__ int sh[256];
    const int t = threadIdx.x;
    const int idx = blockIdx.x * 1024 + t * 4;
    int v[4];
    int s = 0;
#pragma unroll
    for (int j = 0; j < 4; ++j) {
        int x = (idx + j < n) ? data[idx + j] : 0;
        s += x;
        v[j] = s;
    }
    sh[t] = s;
    __syncthreads();
    for (int o = 1; o < 256; o <<= 1) {
        int x = (t >= o) ? sh[t - o] : 0;
        __syncthreads();
        sh[t] += x;
        __syncthreads();
    }
    const int prev = sh[t] - s;
#pragma unroll
    for (int j = 0; j < 4; ++j) {
        if (idx + j < n) data[idx + j] = v[j] + prev;
    }
    if (t == 255) sums[blockIdx.x] = sh[255];
}

__global__ __launch_bounds__(256) void scan2_kernel(int* __restrict__ sums, int nb) {
    __shared__ int sh[256];
    const int t = threadIdx.x;
    sh[t] = (t < nb) ? sums[t] : 0;
    __syncthreads();
    for (int o = 1; o < 256; o <<= 1) {
        int x = (t >= o) ? sh[t - o] : 0;
        __syncthreads();
        sh[t] += x;
        __syncthreads();
    }
    if (t < nb) sums[t] = sh[t];
}

// scan3 + cursor init fused (cursor[i] = final csr_off[i])
__global__ void scan3_kernel(int* __restrict__ data, const int* __restrict__ sums,
                             int* __restrict__ cursor, int n, int N) {
    int i = blockIdx.x * blockDim.x + threadIdx.x;
    if (i >= n) return;
    int b = i >> 10;
    int v = data[i];
    if (b > 0) { v += sums[b - 1]; data[i] = v; }
    if (i < N) cursor[i] = v;
}

__global__ void fill_kernel(const int* __restrict__ src, const int* __restrict__ dst,
                            int* __restrict__ cursor, int* __restrict__ sorted_src, int E) {
    int e = blockIdx.x * blockDim.x + threadIdx.x;
    if (e >= E) return;
    int p = atomicAdd(&cursor[dst[e]], 1);
    sorted_src[p] = src[e];
}

// ===========================================================================
// prep kernels
// ===========================================================================
__global__ void cvt_x_kernel(const float* __restrict__ x, __hip_bfloat16* __restrict__ xb,
                             int N, int total /* Npad*128 */) {
    int i = blockIdx.x * blockDim.x + threadIdx.x;
    if (i >= total) return;
    int n = i >> 7;
    float v = (n < N) ? x[i] : 0.f;
    xb[i] = __float2bfloat16(v);
}

// all 6 weight transposes in one kernel.
// slot 0: K=128 (w1 of layer0), slots 1..5: K=256.
__global__ void wt_all_kernel(const float* __restrict__ w0, const float* __restrict__ w1,
                              const float* __restrict__ w2, const float* __restrict__ w3,
                              const float* __restrict__ w4, const float* __restrict__ w5,
                              __hip_bfloat16* __restrict__ o0, __hip_bfloat16* __restrict__ o1,
                              __hip_bfloat16* __restrict__ o2, __hip_bfloat16* __restrict__ o3,
                              __hip_bfloat16* __restrict__ o4, __hip_bfloat16* __restrict__ o5) {
    int i = blockIdx.x * blockDim.x + threadIdx.x;
    const int S0 = 256 * 128, S = 256 * 256;
    if (i < S0) {
        int m = i / 128, k = i - m * 128;
        o0[i] = __float2bfloat16(w0[k * 256 + m]);
        return;
    }
    i -= S0;
    int mi = i / S, j = i - mi * S;
    if (mi >= 5) return;
    int m = j >> 8, k = j & 255;
    const float* Wp; __hip_bfloat16* Op;
    switch (mi) {
        case 0: Wp = w1; Op = o1; break;
        case 1: Wp = w2; Op = o2; break;
        case 2: Wp = w3; Op = o3; break;
        case 3: Wp = w4; Op = o4; break;
        default: Wp = w5; Op = o5; break;
    }
    Op[j] = __float2bfloat16(Wp[k * 256 + m]);
}

// scale/shift folds for all 6 GEMM epilogues: ss[slot*512 + c] = scale,
// ss[slot*512 + 256 + c] = shift.  slot 2i = (bias+BN of layer i), 2i+1 = bias2.
__global__ void prep_ss_kernel(
    const float* __restrict__ g0, const float* __restrict__ be0, const float* __restrict__ m0,
    const float* __restrict__ v0, const float* __restrict__ b10, const float* __restrict__ b20,
    const float* __restrict__ g1, const float* __restrict__ be1, const float* __restrict__ m1,
    const float* __restrict__ v1, const float* __restrict__ b11, const float* __restrict__ b21,
    const float* __restrict__ g2, const float* __restrict__ be2, const float* __restrict__ m2,
    const float* __restrict__ v2, const float* __restrict__ b12, const float* __restrict__ b22,
    float* __restrict__ ss) {
    const int layer = blockIdx.x;  // 0..2
    const int c = threadIdx.x;     // 0..255
    const float *g, *be, *m, *v, *b1, *b2;
    switch (layer) {
        case 0: g = g0; be = be0; m = m0; v = v0; b1 = b10; b2 = b20; break;
        case 1: g = g1; be = be1; m = m1; v = v1; b1 = b11; b2 = b21; break;
        default: g = g2; be = be2; m = m2; v = v2; b1 = b12; b2 = b22; break;
    }
    float r = rsqrtf(v[c] + BN_EPS);
    float s = g[c] * r;
    ss[(2 * layer) * 512 + c] = s;
    ss[(2 * layer) * 512 + 256 + c] = (b1[c] - m[c]) * s + be[c];
    ss[(2 * layer + 1) * 512 + c] = 1.f;
    ss[(2 * layer + 1) * 512 + 256 + c] = b2[c];
}

// ===========================================================================
// fused aggregate: out[n] = h[n] + sum_{e in CSR(n)} h[src[e]]  (bf16 in/out)
// C/8 lanes per node, 16B chunks; 2-way edge unroll for latency hiding.
// ===========================================================================
template <int C>
__global__ __launch_bounds__(256) void agg_fused(const __hip_bfloat16* __restrict__ h,
                                                 const int* __restrict__ off,
                                                 const int* __restrict__ ssrc,
                                                 __hip_bfloat16* __restrict__ out, int N) {
    constexpr int L = C / 8;
    int t = blockIdx.x * blockDim.x + threadIdx.x;
    int n = t / L;
    if (n >= N) return;
    int c8 = t - n * L;
    const uint4* hp = (const uint4*)h;

    float acc[8];
    {
        uint4 sv = hp[(size_t)n * L + c8];
        const unsigned u[4] = {sv.x, sv.y, sv.z, sv.w};
#pragma unroll
        for (int j = 0; j < 4; ++j) {
            acc[2 * j]     = __uint_as_float(u[j] << 16);
            acc[2 * j + 1] = __uint_as_float(u[j] & 0xffff0000u);
        }
    }
    const int e0 = off[n], e1 = off[n + 1];
    int e = e0;
    for (; e + 2 <= e1; e += 2) {
        int s0 = ssrc[e], s1 = ssrc[e + 1];
        uint4 a = hp[(size_t)s0 * L + c8];
        uint4 b = hp[(size_t)s1 * L + c8];
        const unsigned ua[4] = {a.x, a.y, a.z, a.w};
        const unsigned ub[4] = {b.x, b.y, b.z, b.w};
#pragma unroll
        for (int j = 0; j < 4; ++j) {
            acc[2 * j]     += __uint_as_float(ua[j] << 16);
            acc[2 * j + 1] += __uint_as_float(ua[j] & 0xffff0000u);
            acc[2 * j]     += __uint_as_float(ub[j] << 16);
            acc[2 * j + 1] += __uint_as_float(ub[j] & 0xffff0000u);
        }
    }
    if (e < e1) {
        int s0 = ssrc[e];
        uint4 a = hp[(size_t)s0 * L + c8];
        const unsigned ua[4] = {a.x, a.y, a.z, a.w};
#pragma unroll
        for (int j = 0; j < 4; ++j) {
            acc[2 * j]     += __uint_as_float(ua[j] << 16);
            acc[2 * j + 1] += __uint_as_float(ua[j] & 0xffff0000u);
        }
    }
    unsigned o[4];
#pragma unroll
    for (int j = 0; j < 4; ++j) {
        __hip_bfloat16 a = __float2bfloat16(acc[2 * j]);
        __hip_bfloat16 b = __float2bfloat16(acc[2 * j + 1]);
        unsigned short ua = *(unsigned short*)&a, ub = *(unsigned short*)&b;
        o[j] = (unsigned)ua | ((unsigned)ub << 16);
    }
    ((uint4*)out)[(size_t)n * L + c8] = make_uint4(o[0], o[1], o[2], o[3]);
}

// ===========================================================================
// MFMA GEMM: C[Npad,256] = relu( (A[Npad,K] @ W[K,256]) * sc + sh )
// Wt = W^T [256][K] bf16. Block 128x128, 4 waves (2x2), 64x64/wave, BK=64.
// Double-buffered LDS: stage tile t+1 BEFORE computing tile t (T3 2-phase).
// ===========================================================================
template <int K>
__global__ __launch_bounds__(256) void gemm_mfma(
    const __hip_bfloat16* __restrict__ A,
    const __hip_bfloat16* __restrict__ Wt,
    const float* __restrict__ sc, const float* __restrict__ sh,
    __hip_bfloat16* __restrict__ C) {
    __shared__ short ldsA[2][128 * 64];  // [buf][128 rows][128 B], swizzled content
    __shared__ short ldsB[2][128 * 64];

    const int tid = threadIdx.x;
    const int l = tid & 63;
    const int w = tid >> 6;
    const int wr = w >> 1, wc = w & 1;
    const int rb = blockIdx.x >> 1;
    const int cb = blockIdx.x & 1;
    const int row0 = rb * 128;
    const int col0 = cb * 128;

    f32x4 acc[4][4] = {};

    // staging addressing: lane l covers row += l>>3, byte slot (l&7)*16,
    // source pre-XORed so LDS holds the swizzled tile (m173 pattern)
    const int swz_st = ((l & 7) * 16) ^ ((l >> 3) << 4);
    const char* Ab = (const char*)A + (size_t)(row0 + w * 32 + (l >> 3)) * (K * 2) + swz_st;
    const char* Bb = (const char*)Wt + (size_t)(col0 + w * 32 + (l >> 3)) * (K * 2) + swz_st;

    // fragment-read constants
    const int fr_row = l & 15;
    const int fr_sl = (l >> 4) * 16;
    const int fr_x = (l & 7) << 4;

    constexpr int NT = K / 64;

    auto stage = [&](int buf, int t) {
#pragma unroll
        for (int i = 0; i < 4; ++i) {
            gll16(Ab + (size_t)t * 128 + (size_t)(i * 8) * (K * 2),
                  (char*)&ldsA[buf][0] + (w * 32 + i * 8) * 128);
            gll16(Bb + (size_t)t * 128 + (size_t)(i * 8) * (K * 2),
                  (char*)&ldsB[buf][0] + (w * 32 + i * 8) * 128);
        }
    };

    // prologue: tile 0
    stage(0, 0);
    asm volatile("s_waitcnt vmcnt(0)" ::: "memory");
    __builtin_amdgcn_s_barrier();

    int cur = 0;
#pragma unroll
    for (int t = 0; t < NT; ++t) {
        if (t + 1 < NT) stage(cur ^ 1, t + 1);  // prefetch next tile

#pragma unroll
        for (int k0 = 0; k0 < 2; ++k0) {
            short8 af[4], bf[4];
            const int byt = (k0 * 64 + fr_sl) ^ fr_x;
#pragma unroll
            for (int mi = 0; mi < 4; ++mi) {
                int row = wr * 64 + mi * 16 + fr_row;
                af[mi] = *(const short8*)((const char*)&ldsA[cur][0] + row * 128 + byt);
            }
#pragma unroll
            for (int ni = 0; ni < 4; ++ni) {
                int col = wc * 64 + ni * 16 + fr_row;
                bf[ni] = *(const short8*)((const char*)&ldsB[cur][0] + col * 128 + byt);
            }
#pragma unroll
            for (int mi = 0; mi < 4; ++mi)
#pragma unroll
                for (int ni = 0; ni < 4; ++ni)
                    acc[mi][ni] = __builtin_amdgcn_mfma_f32_16x16x32_bf16(
                        af[mi], bf[ni], acc[mi][ni], 0, 0, 0);
        }

        if (t + 1 < NT) {
            asm volatile("s_waitcnt vmcnt(0)" ::: "memory");  // drains t+1's stage,
            __builtin_amdgcn_s_barrier();                     // hidden under the MFMAs above
            cur ^= 1;
        }
    }

    // epilogue: C/D layout col=lane&15, row=(lane>>4)*4+reg (m89-verified)
    const int lr = l >> 4;
    const int lc = l & 15;
#pragma unroll
    for (int ni = 0; ni < 4; ++ni) {
        const int col = col0 + wc * 64 + ni * 16 + lc;
        const float s = sc[col], t = sh[col];
#pragma unroll
        for (int mi = 0; mi < 4; ++mi) {
            const int grow = row0 + wr * 64 + mi * 16 + lr * 4;
#pragma unroll
            for (int r = 0; r < 4; ++r) {
                float vv = acc[mi][ni][r] * s + t;
                vv = fmaxf(vv, 0.f);
                C[(size_t)(grow + r) * 256 + col] = __float2bfloat16(vv);
            }
        }
    }
}

// ===========================================================================
// segmented pool (bf16 in, fp32 out), one block per graph
// ===========================================================================
__device__ __forceinline__ int lower_bound_dev(const int* __restrict__ a, int n, int key) {
    int lo = 0, hi = n;
    while (lo < hi) {
        int mid = (lo + hi) >> 1;
        if (a[mid] < key) lo = mid + 1; else hi = mid;
    }
    return lo;
}

__global__ __launch_bounds__(256) void pool_seg_kernel(const __hip_bfloat16* __restrict__ h,
                                                       const int* __restrict__ batch,
                                                       float* __restrict__ pooled, int N) {
    __shared__ int seg[2];
    const int g = blockIdx.x;
    if (threadIdx.x == 0) seg[0] = lower_bound_dev(batch, N, g);
    if (threadIdx.x == 1) seg[1] = lower_bound_dev(batch, N, g + 1);
    __syncthreads();
    const int c = threadIdx.x;
    float acc = 0.f;
    for (int n = seg[0]; n < seg[1]; ++n) acc += __bfloat162float(h[(size_t)n * 256 + c]);
    pooled[(size_t)g * 256 + c] = acc;
}

// ===========================================================================
// head: out[g] = relu(bn(pooled[g]@w0 + b0)) @ w1 + b1
// ===========================================================================
__global__ __launch_bounds__(128) void head_kernel(
    const float* __restrict__ pooled,
    const float* __restrict__ w0, const float* __restrict__ b0,
    const float* __restrict__ g, const float* __restrict__ be,
    const float* __restrict__ m, const float* __restrict__ v,
    const float* __restrict__ w1, const float* __restrict__ b1,
    float* __restrict__ out) {
    __shared__ float row[256];
    __shared__ float red[128];
    const int gid = blockIdx.x;
    const int j = threadIdx.x;

    row[j]       = pooled[(size_t)gid * 256 + j];
    row[j + 128] = pooled[(size_t)gid * 256 + 128 + j];
    __syncthreads();

    float acc = b0[j];
#pragma unroll 8
    for (int k = 0; k < 256; ++k) acc += row[k] * w0[k * 128 + j];

    float h = g[j] * (acc - m[j]) * rsqrtf(v[j] + BN_EPS) + be[j];
    h = fmaxf(h, 0.f) * w1[j];
    red[j] = h;
    __syncthreads();
    for (int s = 64; s > 0; s >>= 1) {
        if (j < s) red[j] += red[j + s];
        __syncthreads();
    }
    if (j == 0) out[gid] = red[0] + b1[0];
}

// ===========================================================================
// launch
// ===========================================================================
extern "C" void kernel_launch(void* const* d_in, const int* in_sizes, int n_in,
                              void* d_out, int out_size, void* d_ws, size_t ws_size,
                              hipStream_t stream) {
    const float* x    = (const float*)d_in[0];
    const int* eidx   = (const int*)d_in[1];
    const int* batch  = (const int*)d_in[2];

    const int N = in_sizes[0] / 128;
    const int E = in_sizes[1] / 2;
    const int G = out_size;

    const int* src = eidx;
    const int* dst = eidx + E;

    const float* cw1[3]; const float* cb1[3]; const float* cg[3]; const float* cbe[3];
    const float* cm[3];  const float* cv[3];  const float* cw2[3]; const float* cb2[3];
    for (int i = 0; i < 3; ++i) {
        int b = 3 + i * 8;
        cw1[i] = (const float*)d_in[b + 0];
        cb1[i] = (const float*)d_in[b + 1];
        cg[i]  = (const float*)d_in[b + 2];
        cbe[i] = (const float*)d_in[b + 3];
        cm[i]  = (const float*)d_in[b + 4];
        cv[i]  = (const float*)d_in[b + 5];
        cw2[i] = (const float*)d_in[b + 6];
        cb2[i] = (const float*)d_in[b + 7];
    }
    const float* l0_w  = (const float*)d_in[27];
    const float* l0_b  = (const float*)d_in[28];
    const float* l0_g  = (const float*)d_in[29];
    const float* l0_be = (const float*)d_in[30];
    const float* l0_m  = (const float*)d_in[31];
    const float* l0_v  = (const float*)d_in[32];
    const float* l1_w  = (const float*)d_in[33];
    const float* l1_b  = (const float*)d_in[34];

    float* outp = (float*)d_out;

    // ---- workspace layout ----
    const int nrb  = (N + 127) / 128;
    const int Npad = nrb * 128;
    const size_t SB = (size_t)Npad * 256 * 2;   // bf16 [Npad][256]
    const size_t XB = (size_t)Npad * 128 * 2;   // bf16 [Npad][128]
    const size_t PB = (size_t)G * 256 * 4;
    const size_t WTB = (size_t)256 * 256 * 2;

    char* ws = (char*)d_ws;
    size_t o = 0;
    __hip_bfloat16* B1 = (__hip_bfloat16*)(ws + o); o += SB;
    __hip_bfloat16* B2 = (__hip_bfloat16*)(ws + o); o += SB;
    __hip_bfloat16* B3 = (__hip_bfloat16*)(ws + o); o += SB;
    __hip_bfloat16* xb = (__hip_bfloat16*)(ws + o); o += XB;
    float* pooled      = (float*)(ws + o);       o += PB;
    __hip_bfloat16* wt[6];
    for (int i = 0; i < 6; ++i) { wt[i] = (__hip_bfloat16*)(ws + o); o += WTB; }
    float* ss          = (float*)(ws + o);       o += 6 * 512 * 4;
    int* csr_off    = (int*)(ws + o); o += (size_t)(N + 1) * 4;
    int* cursor     = (int*)(ws + o); o += (size_t)N * 4;
    int* sorted_src = (int*)(ws + o); o += (size_t)E * 4;
    int* sums       = (int*)(ws + o); o += 256 * 4;
    if (ws_size < o) return;  // clean failure instead of page fault

    const dim3 blk(256);

    // ---- prep: conversions, weight transposes, epilogue scale/shift folds ----
    {
        int total = Npad * 128;
        cvt_x_kernel<<<(total + 255) / 256, blk, 0, stream>>>(x, xb, N, total);
    }
    {
        int total = 256 * 128 + 5 * 256 * 256;
        wt_all_kernel<<<(total + 255) / 256, blk, 0, stream>>>(
            cw1[0], cw2[0], cw1[1], cw2[1], cw1[2], cw2[2],
            wt[0], wt[1], wt[2], wt[3], wt[4], wt[5]);
    }
    prep_ss_kernel<<<3, blk, 0, stream>>>(
        cg[0], cbe[0], cm[0], cv[0], cb1[0], cb2[0],
        cg[1], cbe[1], cm[1], cv[1], cb1[1], cb2[1],
        cg[2], cbe[2], cm[2], cv[2], cb1[2], cb2[2], ss);

    // ---- CSR build ----
    {
        const int n_off = N + 1;
        hipMemsetAsync(csr_off, 0, (size_t)n_off * sizeof(int), stream);
        hist_kernel<<<(E + 255) / 256, blk, 0, stream>>>(dst, csr_off, E);
        const int nb = (n_off + 1023) / 1024;
        scan1_kernel<<<nb, blk, 0, stream>>>(csr_off, sums, n_off);
        scan2_kernel<<<1, blk, 0, stream>>>(sums, nb);
        scan3_kernel<<<(n_off + 255) / 256, blk, 0, stream>>>(csr_off, sums, cursor, n_off, N);
        fill_kernel<<<(E + 255) / 256, blk, 0, stream>>>(src, dst, cursor, sorted_src, E);
    }

    const int gemm_grid = nrb * 2;
    auto SC = [&](int i) { return ss + i * 512; };
    auto SH = [&](int i) { return ss + i * 512 + 256; };

    // ---------------- layer 0 (128 -> 256) ----------------
    {
        int total = N * 16;
        agg_fused<128><<<(total + 255) / 256, blk, 0, stream>>>(xb, csr_off, sorted_src, B1, N);
    }
    gemm_mfma<128><<<gemm_grid, blk, 0, stream>>>(B1, wt[0], SC(0), SH(0), B2);
    gemm_mfma<256><<<gemm_grid, blk, 0, stream>>>(B2, wt[1], SC(1), SH(1), B3);

    // ---------------- layer 1 ----------------
    {
        int total = N * 32;
        agg_fused<256><<<(total + 255) / 256, blk, 0, stream>>>(B3, csr_off, sorted_src, B1, N);
    }
    gemm_mfma<256><<<gemm_grid, blk, 0, stream>>>(B1, wt[2], SC(2), SH(2), B2);
    gemm_mfma<256><<<gemm_grid, blk, 0, stream>>>(B2, wt[3], SC(3), SH(3), B3);

    // ---------------- layer 2 ----------------
    {
        int total = N * 32;
        agg_fused<256><<<(total + 255) / 256, blk, 0, stream>>>(B3, csr_off, sorted_src, B1, N);
    }
    gemm_mfma<256><<<gemm_grid, blk, 0, stream>>>(B1, wt[4], SC(4), SH(4), B2);
    gemm_mfma<256><<<gemm_grid, blk, 0, stream>>>(B2, wt[5], SC(5), SH(5), B3);

    // ---------------- pooling + head ----------------
    pool_seg_kernel<<<G, blk, 0, stream>>>(B3, batch, pooled, N);
    head_kernel<<<G, dim3(128), 0, stream>>>(pooled, l0_w, l0_b, l0_g, l0_be, l0_m, l0_v,
                                             l1_w, l1_b, outp);
}

// Round 6
// 437.119 us; speedup vs baseline: 14.6028x; 1.0525x over previous
//
#include <hip/hip_runtime.h>
#include <hip/hip_bf16.h>

#define BN_EPS 1e-5f

typedef __attribute__((ext_vector_type(8))) short short8;
typedef __attribute__((ext_vector_type(4))) float f32x4;

__device__ __forceinline__ void gll16(const void* g, void* l) {
    __builtin_amdgcn_global_load_lds(
        (const __attribute__((address_space(1))) unsigned int*)g,
        (__attribute__((address_space(3))) unsigned int*)l, 16, 0, 0);
}

__device__ __forceinline__ unsigned pack_bf2(float a, float b) {
    __hip_bfloat16 ba = __float2bfloat16(a);
    __hip_bfloat16 bb = __float2bfloat16(b);
    return (unsigned)(*(unsigned short*)&ba) | ((unsigned)(*(unsigned short*)&bb) << 16);
}

// ===========================================================================
// CSR construction (graph identical across the 3 layers)
// ===========================================================================
__global__ void hist_kernel(const int* __restrict__ dst, int* __restrict__ off, int E) {
    int e = blockIdx.x * blockDim.x + threadIdx.x;
    if (e < E) atomicAdd(&off[dst[e] + 1], 1);
}

__global__ __launch_bounds__(256) void scan1_kernel(int* __restrict__ data,
                                                    int* __restrict__ sums, int n) {
    __shared__ int sh[256];
    const int t = threadIdx.x;
    const int idx = blockIdx.x * 1024 + t * 4;
    int v[4];
    int s = 0;
#pragma unroll
    for (int j = 0; j < 4; ++j) {
        int x = (idx + j < n) ? data[idx + j] : 0;
        s += x;
        v[j] = s;
    }
    sh[t] = s;
    __syncthreads();
    for (int o = 1; o < 256; o <<= 1) {
        int x = (t >= o) ? sh[t - o] : 0;
        __syncthreads();
        sh[t] += x;
        __syncthreads();
    }
    const int prev = sh[t] - s;
#pragma unroll
    for (int j = 0; j < 4; ++j) {
        if (idx + j < n) data[idx + j] = v[j] + prev;
    }
    if (t == 255) sums[blockIdx.x] = sh[255];
}

__global__ __launch_bounds__(256) void scan2_kernel(int* __restrict__ sums, int nb) {
    __shared__ int sh[256];
    const int t = threadIdx.x;
    sh[t] = (t < nb) ? sums[t] : 0;
    __syncthreads();
    for (int o = 1; o < 256; o <<= 1) {
        int x = (t >= o) ? sh[t - o] : 0;
        __syncthreads();
        sh[t] += x;
        __syncthreads();
    }
    if (t < nb) sums[t] = sh[t];
}

__global__ void scan3_kernel(int* __restrict__ data, const int* __restrict__ sums,
                             int* __restrict__ cursor, int n, int N) {
    int i = blockIdx.x * blockDim.x + threadIdx.x;
    if (i >= n) return;
    int b = i >> 10;
    int v = data[i];
    if (b > 0) { v += sums[b - 1]; data[i] = v; }
    if (i < N) cursor[i] = v;
}

__global__ void fill_kernel(const int* __restrict__ src, const int* __restrict__ dst,
                            int* __restrict__ cursor, int* __restrict__ sorted_src, int E) {
    int e = blockIdx.x * blockDim.x + threadIdx.x;
    if (e >= E) return;
    int p = atomicAdd(&cursor[dst[e]], 1);
    sorted_src[p] = src[e];
}

// ===========================================================================
// prep kernels
// ===========================================================================
__global__ void cvt_x_kernel(const float* __restrict__ x, __hip_bfloat16* __restrict__ xb,
                             int N, int total /* Npad*128 */) {
    int i = blockIdx.x * blockDim.x + threadIdx.x;
    if (i >= total) return;
    int n = i >> 7;
    float v = (n < N) ? x[i] : 0.f;
    xb[i] = __float2bfloat16(v);
}

__global__ void wt_all_kernel(const float* __restrict__ w0, const float* __restrict__ w1,
                              const float* __restrict__ w2, const float* __restrict__ w3,
                              const float* __restrict__ w4, const float* __restrict__ w5,
                              __hip_bfloat16* __restrict__ o0, __hip_bfloat16* __restrict__ o1,
                              __hip_bfloat16* __restrict__ o2, __hip_bfloat16* __restrict__ o3,
                              __hip_bfloat16* __restrict__ o4, __hip_bfloat16* __restrict__ o5) {
    int i = blockIdx.x * blockDim.x + threadIdx.x;
    const int S0 = 256 * 128, S = 256 * 256;
    if (i < S0) {
        int m = i / 128, k = i - m * 128;
        o0[i] = __float2bfloat16(w0[k * 256 + m]);
        return;
    }
    i -= S0;
    int mi = i / S, j = i - mi * S;
    if (mi >= 5) return;
    int m = j >> 8, k = j & 255;
    const float* Wp; __hip_bfloat16* Op;
    switch (mi) {
        case 0: Wp = w1; Op = o1; break;
        case 1: Wp = w2; Op = o2; break;
        case 2: Wp = w3; Op = o3; break;
        case 3: Wp = w4; Op = o4; break;
        default: Wp = w5; Op = o5; break;
    }
    Op[j] = __float2bfloat16(Wp[k * 256 + m]);
}

__global__ void prep_ss_kernel(
    const float* __restrict__ g0, const float* __restrict__ be0, const float* __restrict__ m0,
    const float* __restrict__ v0, const float* __restrict__ b10, const float* __restrict__ b20,
    const float* __restrict__ g1, const float* __restrict__ be1, const float* __restrict__ m1,
    const float* __restrict__ v1, const float* __restrict__ b11, const float* __restrict__ b21,
    const float* __restrict__ g2, const float* __restrict__ be2, const float* __restrict__ m2,
    const float* __restrict__ v2, const float* __restrict__ b12, const float* __restrict__ b22,
    float* __restrict__ ss) {
    const int layer = blockIdx.x;
    const int c = threadIdx.x;
    const float *g, *be, *m, *v, *b1, *b2;
    switch (layer) {
        case 0: g = g0; be = be0; m = m0; v = v0; b1 = b10; b2 = b20; break;
        case 1: g = g1; be = be1; m = m1; v = v1; b1 = b11; b2 = b21; break;
        default: g = g2; be = be2; m = m2; v = v2; b1 = b12; b2 = b22; break;
    }
    float r = rsqrtf(v[c] + BN_EPS);
    float s = g[c] * r;
    ss[(2 * layer) * 512 + c] = s;
    ss[(2 * layer) * 512 + 256 + c] = (b1[c] - m[c]) * s + be[c];
    ss[(2 * layer + 1) * 512 + c] = 1.f;
    ss[(2 * layer + 1) * 512 + 256 + c] = b2[c];
}

// ===========================================================================
// fused aggregate: out[n] = h[n] + sum_{e in CSR(n)} h[src[e]]  (bf16 in/out)
// ===========================================================================
template <int C>
__global__ __launch_bounds__(256) void agg_fused(const __hip_bfloat16* __restrict__ h,
                                                 const int* __restrict__ off,
                                                 const int* __restrict__ ssrc,
                                                 __hip_bfloat16* __restrict__ out, int N) {
    constexpr int L = C / 8;
    int t = blockIdx.x * blockDim.x + threadIdx.x;
    int n = t / L;
    if (n >= N) return;
    int c8 = t - n * L;
    const uint4* hp = (const uint4*)h;

    float acc[8];
    {
        uint4 sv = hp[(size_t)n * L + c8];
        const unsigned u[4] = {sv.x, sv.y, sv.z, sv.w};
#pragma unroll
        for (int j = 0; j < 4; ++j) {
            acc[2 * j]     = __uint_as_float(u[j] << 16);
            acc[2 * j + 1] = __uint_as_float(u[j] & 0xffff0000u);
        }
    }
    const int e0 = off[n], e1 = off[n + 1];
    int e = e0;
    for (; e + 2 <= e1; e += 2) {
        int s0 = ssrc[e], s1 = ssrc[e + 1];
        uint4 a = hp[(size_t)s0 * L + c8];
        uint4 b = hp[(size_t)s1 * L + c8];
        const unsigned ua[4] = {a.x, a.y, a.z, a.w};
        const unsigned ub[4] = {b.x, b.y, b.z, b.w};
#pragma unroll
        for (int j = 0; j < 4; ++j) {
            acc[2 * j]     += __uint_as_float(ua[j] << 16);
            acc[2 * j + 1] += __uint_as_float(ua[j] & 0xffff0000u);
            acc[2 * j]     += __uint_as_float(ub[j] << 16);
            acc[2 * j + 1] += __uint_as_float(ub[j] & 0xffff0000u);
        }
    }
    if (e < e1) {
        int s0 = ssrc[e];
        uint4 a = hp[(size_t)s0 * L + c8];
        const unsigned ua[4] = {a.x, a.y, a.z, a.w};
#pragma unroll
        for (int j = 0; j < 4; ++j) {
            acc[2 * j]     += __uint_as_float(ua[j] << 16);
            acc[2 * j + 1] += __uint_as_float(ua[j] & 0xffff0000u);
        }
    }
    unsigned o[4];
#pragma unroll
    for (int j = 0; j < 4; ++j) o[j] = pack_bf2(acc[2 * j], acc[2 * j + 1]);
    ((uint4*)out)[(size_t)n * L + c8] = make_uint4(o[0], o[1], o[2], o[3]);
}

// ===========================================================================
// fused MLP layer: C = relu( relu(bn(A@W1)) @ W2 + b2 ), all per 128-row block.
// A [Npad][K1] bf16; W1t [256][K1], W2t [256][256] (transposed, bf16).
// 512 threads = 8 waves (2 row-halves x 4 col-quarters), wave tile 64x64.
// LDS: bufAT 64KB (A panel, then intermediate T), bufW 2x32KB (W tiles, dbuf).
// GEMM1 uses swapped operands mfma(Wfrag, Afrag) so each lane holds 4
// consecutive T-columns per reg-quad -> packed 8B ds_write of T.
// In-place safe when K1==256 (block reads only its own rows, all reads
// complete before epilogue writes).
// ===========================================================================
template <int K1>
__global__ __launch_bounds__(512) void mlp_fused(
    const __hip_bfloat16* __restrict__ A,
    const __hip_bfloat16* __restrict__ W1t,
    const __hip_bfloat16* __restrict__ W2t,
    const float* __restrict__ ss1, const float* __restrict__ ss2,
    __hip_bfloat16* __restrict__ C) {
    __shared__ __align__(16) char bufAT[64 * 1024];
    __shared__ __align__(16) char bufW[2][32 * 1024];

    const int tid = threadIdx.x;
    const int l   = tid & 63;
    const int w   = tid >> 6;   // 0..7
    const int wr  = w >> 2;     // 0..1 row half
    const int wc  = w & 3;      // 0..3 col quarter
    const size_t row0 = (size_t)blockIdx.x * 128;

    constexpr int ROWB = K1 * 2;        // A row bytes
    constexpr int NT1  = K1 / 64;       // GEMM1 K-tiles
    constexpr int NIA  = 128 * ROWB / 1024;
    constexpr int RPI  = 1024 / ROWB;   // A rows per gll16 instr

    const int lswz = (l & 7) << 4;      // frag-read XOR (row&7==l&7 for all frags)

    // ---- stage A panel (pre-swizzled source, linear LDS dest) ----
    {
        const char* Ab = (const char*)(A + row0 * K1);
#pragma unroll
        for (int i = w; i < NIA; i += 8) {
            int row = i * RPI + (l * 16) / ROWB;
            int byt = ((l * 16) % ROWB) ^ ((row & 7) << 4);
            gll16(Ab + (size_t)row * ROWB + byt, bufAT + i * 1024);
        }
    }
    // ---- W tile stager: tile t = k-window [t*64, t*64+64) of Wsrc[256][Krow2/2] ----
    auto stageW = [&](const __hip_bfloat16* Wsrc, int Krow2, int t, int buf) {
        const char* Wb = (const char*)Wsrc;
#pragma unroll
        for (int i = w; i < 32; i += 8) {
            int c = i * 8 + (l >> 3);
            int byt = ((l & 7) * 16) ^ ((c & 7) << 4);
            gll16(Wb + (size_t)c * Krow2 + t * 128 + byt, bufW[buf] + i * 1024);
        }
    };
    stageW(W1t, ROWB, 0, 0);
    __syncthreads();

    // ================= GEMM1: T[n][m] = sum_k A[n][k] W1[k][m] =================
    f32x4 acc1[4][4] = {};  // [mi = W-col frag][nj = A-row frag]
    int buf = 0;
#pragma unroll
    for (int t = 0; t < NT1; ++t) {
        if (t + 1 < NT1) stageW(W1t, ROWB, t + 1, buf ^ 1);
        else             stageW(W2t, 512, 0, buf ^ 1);
#pragma unroll
        for (int k0 = 0; k0 < 2; ++k0) {
            short8 wf[4], af[4];
            const int wbyt = (k0 * 64 + (l >> 4) * 16) ^ lswz;
            const int abyt = (t * 128 + k0 * 64 + (l >> 4) * 16) ^ lswz;
#pragma unroll
            for (int i = 0; i < 4; ++i) {
                const int c = wc * 64 + i * 16 + (l & 15);
                wf[i] = *(const short8*)(bufW[buf] + c * 128 + wbyt);
                const int r = wr * 64 + i * 16 + (l & 15);
                af[i] = *(const short8*)(bufAT + r * ROWB + abyt);
            }
#pragma unroll
            for (int mi = 0; mi < 4; ++mi)
#pragma unroll
                for (int nj = 0; nj < 4; ++nj)
                    acc1[mi][nj] = __builtin_amdgcn_mfma_f32_16x16x32_bf16(
                        wf[mi], af[nj], acc1[mi][nj], 0, 0, 0);
        }
        __syncthreads();  // drains next-tile stage; all A/W reads of step t done
        buf ^= 1;
    }

    // ---- T-write: bn+relu, pack 4 consecutive cols per 8B ds_write ----
    // acc1 elem: T[row = wr*64+nj*16+(l&15)][col m = wc*64+mi*16+(l>>4)*4 + r]
#pragma unroll
    for (int mi = 0; mi < 4; ++mi) {
        const int m0 = wc * 64 + mi * 16 + (l >> 4) * 4;
        const float4 s4 = *(const float4*)(ss1 + m0);
        const float4 h4 = *(const float4*)(ss1 + 256 + m0);
        const int byt = (m0 * 2) ^ lswz;
#pragma unroll
        for (int nj = 0; nj < 4; ++nj) {
            const int n = wr * 64 + nj * 16 + (l & 15);
            const float v0 = fmaxf(acc1[mi][nj][0] * s4.x + h4.x, 0.f);
            const float v1 = fmaxf(acc1[mi][nj][1] * s4.y + h4.y, 0.f);
            const float v2 = fmaxf(acc1[mi][nj][2] * s4.z + h4.z, 0.f);
            const float v3 = fmaxf(acc1[mi][nj][3] * s4.w + h4.w, 0.f);
            *(uint2*)(bufAT + n * 512 + byt) = make_uint2(pack_bf2(v0, v1), pack_bf2(v2, v3));
        }
    }
    __syncthreads();  // T visible to all waves

    // ================= GEMM2: C[n][c] = sum_k T[n][k] W2[k][c] =================
    f32x4 acc2[4][4] = {};  // [mi = T-row frag][ni = W2-col frag]
#pragma unroll
    for (int s = 0; s < 4; ++s) {
        if (s < 3) stageW(W2t, 512, s + 1, buf ^ 1);
#pragma unroll
        for (int k0 = 0; k0 < 2; ++k0) {
            short8 tf[4], wf[4];
            const int tbyt = (s * 128 + k0 * 64 + (l >> 4) * 16) ^ lswz;
            const int wbyt = (k0 * 64 + (l >> 4) * 16) ^ lswz;
#pragma unroll
            for (int i = 0; i < 4; ++i) {
                const int r = wr * 64 + i * 16 + (l & 15);
                tf[i] = *(const short8*)(bufAT + r * 512 + tbyt);
                const int c = wc * 64 + i * 16 + (l & 15);
                wf[i] = *(const short8*)(bufW[buf] + c * 128 + wbyt);
            }
#pragma unroll
            for (int mi = 0; mi < 4; ++mi)
#pragma unroll
                for (int ni = 0; ni < 4; ++ni)
                    acc2[mi][ni] = __builtin_amdgcn_mfma_f32_16x16x32_bf16(
                        tf[mi], wf[ni], acc2[mi][ni], 0, 0, 0);
        }
        if (s < 3) { __syncthreads(); buf ^= 1; }
    }

    // ---- epilogue: bias + relu, bf16 store ----
#pragma unroll
    for (int ni = 0; ni < 4; ++ni) {
        const int col = wc * 64 + ni * 16 + (l & 15);
        const float sc = ss2[col], sh = ss2[256 + col];
#pragma unroll
        for (int mi = 0; mi < 4; ++mi) {
            const size_t grow = row0 + wr * 64 + mi * 16 + (l >> 4) * 4;
#pragma unroll
            for (int r = 0; r < 4; ++r) {
                float vv = fmaxf(acc2[mi][ni][r] * sc + sh, 0.f);
                C[(grow + r) * 256 + col] = __float2bfloat16(vv);
            }
        }
    }
}

// ===========================================================================
// segmented pool (bf16 in, fp32 out), one block per graph
// ===========================================================================
__device__ __forceinline__ int lower_bound_dev(const int* __restrict__ a, int n, int key) {
    int lo = 0, hi = n;
    while (lo < hi) {
        int mid = (lo + hi) >> 1;
        if (a[mid] < key) lo = mid + 1; else hi = mid;
    }
    return lo;
}

__global__ __launch_bounds__(256) void pool_seg_kernel(const __hip_bfloat16* __restrict__ h,
                                                       const int* __restrict__ batch,
                                                       float* __restrict__ pooled, int N) {
    __shared__ int seg[2];
    const int g = blockIdx.x;
    if (threadIdx.x == 0) seg[0] = lower_bound_dev(batch, N, g);
    if (threadIdx.x == 1) seg[1] = lower_bound_dev(batch, N, g + 1);
    __syncthreads();
    const int c = threadIdx.x;
    float acc = 0.f;
    for (int n = seg[0]; n < seg[1]; ++n) acc += __bfloat162float(h[(size_t)n * 256 + c]);
    pooled[(size_t)g * 256 + c] = acc;
}

// ===========================================================================
// head
// ===========================================================================
__global__ __launch_bounds__(128) void head_kernel(
    const float* __restrict__ pooled,
    const float* __restrict__ w0, const float* __restrict__ b0,
    const float* __restrict__ g, const float* __restrict__ be,
    const float* __restrict__ m, const float* __restrict__ v,
    const float* __restrict__ w1, const float* __restrict__ b1,
    float* __restrict__ out) {
    __shared__ float row[256];
    __shared__ float red[128];
    const int gid = blockIdx.x;
    const int j = threadIdx.x;

    row[j]       = pooled[(size_t)gid * 256 + j];
    row[j + 128] = pooled[(size_t)gid * 256 + 128 + j];
    __syncthreads();

    float acc = b0[j];
#pragma unroll 8
    for (int k = 0; k < 256; ++k) acc += row[k] * w0[k * 128 + j];

    float h = g[j] * (acc - m[j]) * rsqrtf(v[j] + BN_EPS) + be[j];
    h = fmaxf(h, 0.f) * w1[j];
    red[j] = h;
    __syncthreads();
    for (int s = 64; s > 0; s >>= 1) {
        if (j < s) red[j] += red[j + s];
        __syncthreads();
    }
    if (j == 0) out[gid] = red[0] + b1[0];
}

// ===========================================================================
// launch
// ===========================================================================
extern "C" void kernel_launch(void* const* d_in, const int* in_sizes, int n_in,
                              void* d_out, int out_size, void* d_ws, size_t ws_size,
                              hipStream_t stream) {
    const float* x    = (const float*)d_in[0];
    const int* eidx   = (const int*)d_in[1];
    const int* batch  = (const int*)d_in[2];

    const int N = in_sizes[0] / 128;
    const int E = in_sizes[1] / 2;
    const int G = out_size;

    const int* src = eidx;
    const int* dst = eidx + E;

    const float* cw1[3]; const float* cb1[3]; const float* cg[3]; const float* cbe[3];
    const float* cm[3];  const float* cv[3];  const float* cw2[3]; const float* cb2[3];
    for (int i = 0; i < 3; ++i) {
        int b = 3 + i * 8;
        cw1[i] = (const float*)d_in[b + 0];
        cb1[i] = (const float*)d_in[b + 1];
        cg[i]  = (const float*)d_in[b + 2];
        cbe[i] = (const float*)d_in[b + 3];
        cm[i]  = (const float*)d_in[b + 4];
        cv[i]  = (const float*)d_in[b + 5];
        cw2[i] = (const float*)d_in[b + 6];
        cb2[i] = (const float*)d_in[b + 7];
    }
    const float* l0_w  = (const float*)d_in[27];
    const float* l0_b  = (const float*)d_in[28];
    const float* l0_g  = (const float*)d_in[29];
    const float* l0_be = (const float*)d_in[30];
    const float* l0_m  = (const float*)d_in[31];
    const float* l0_v  = (const float*)d_in[32];
    const float* l1_w  = (const float*)d_in[33];
    const float* l1_b  = (const float*)d_in[34];

    float* outp = (float*)d_out;

    // ---- workspace layout ----
    const int nrb  = (N + 127) / 128;
    const int Npad = nrb * 128;
    const size_t SB = (size_t)Npad * 256 * 2;   // bf16 [Npad][256]
    const size_t XB = (size_t)Npad * 128 * 2;   // bf16 [Npad][128]
    const size_t PB = (size_t)G * 256 * 4;
    const size_t WTB = (size_t)256 * 256 * 2;

    char* ws = (char*)d_ws;
    size_t o = 0;
    __hip_bfloat16* U  = (__hip_bfloat16*)(ws + o); o += SB;
    __hip_bfloat16* V  = (__hip_bfloat16*)(ws + o); o += SB;
    __hip_bfloat16* xb = (__hip_bfloat16*)(ws + o); o += XB;
    float* pooled      = (float*)(ws + o);       o += PB;
    __hip_bfloat16* wt[6];
    for (int i = 0; i < 6; ++i) { wt[i] = (__hip_bfloat16*)(ws + o); o += WTB; }
    float* ss          = (float*)(ws + o);       o += 6 * 512 * 4;
    int* csr_off    = (int*)(ws + o); o += (size_t)(N + 1) * 4;
    int* cursor     = (int*)(ws + o); o += (size_t)N * 4;
    int* sorted_src = (int*)(ws + o); o += (size_t)E * 4;
    int* sums       = (int*)(ws + o); o += 256 * 4;
    if (ws_size < o) return;  // clean failure instead of page fault

    const dim3 blk(256);

    // ---- prep ----
    {
        int total = Npad * 128;
        cvt_x_kernel<<<(total + 255) / 256, blk, 0, stream>>>(x, xb, N, total);
    }
    {
        int total = 256 * 128 + 5 * 256 * 256;
        wt_all_kernel<<<(total + 255) / 256, blk, 0, stream>>>(
            cw1[0], cw2[0], cw1[1], cw2[1], cw1[2], cw2[2],
            wt[0], wt[1], wt[2], wt[3], wt[4], wt[5]);
    }
    prep_ss_kernel<<<3, blk, 0, stream>>>(
        cg[0], cbe[0], cm[0], cv[0], cb1[0], cb2[0],
        cg[1], cbe[1], cm[1], cv[1], cb1[1], cb2[1],
        cg[2], cbe[2], cm[2], cv[2], cb1[2], cb2[2], ss);

    // ---- CSR build ----
    {
        const int n_off = N + 1;
        hipMemsetAsync(csr_off, 0, (size_t)n_off * sizeof(int), stream);
        hist_kernel<<<(E + 255) / 256, blk, 0, stream>>>(dst, csr_off, E);
        const int nb = (n_off + 1023) / 1024;
        scan1_kernel<<<nb, blk, 0, stream>>>(csr_off, sums, n_off);
        scan2_kernel<<<1, blk, 0, stream>>>(sums, nb);
        scan3_kernel<<<(n_off + 255) / 256, blk, 0, stream>>>(csr_off, sums, cursor, n_off, N);
        fill_kernel<<<(E + 255) / 256, blk, 0, stream>>>(src, dst, cursor, sorted_src, E);
    }

    auto SS = [&](int i) { return ss + i * 512; };

    // ---------------- layer 0 (128 -> 256): agg xb->U(128 layout), mlp U->V ----
    {
        int total = N * 16;
        agg_fused<128><<<(total + 255) / 256, blk, 0, stream>>>(xb, csr_off, sorted_src, U, N);
    }
    mlp_fused<128><<<nrb, dim3(512), 0, stream>>>(U, wt[0], wt[1], SS(0), SS(1), V);

    // ---------------- layer 1: agg V->U, mlp U->U (in-place) ----
    {
        int total = N * 32;
        agg_fused<256><<<(total + 255) / 256, blk, 0, stream>>>(V, csr_off, sorted_src, U, N);
    }
    mlp_fused<256><<<nrb, dim3(512), 0, stream>>>(U, wt[2], wt[3], SS(2), SS(3), U);

    // ---------------- layer 2: agg U->V, mlp V->V (in-place) ----
    {
        int total = N * 32;
        agg_fused<256><<<(total + 255) / 256, blk, 0, stream>>>(U, csr_off, sorted_src, V, N);
    }
    mlp_fused<256><<<nrb, dim3(512), 0, stream>>>(V, wt[4], wt[5], SS(4), SS(5), V);

    // ---------------- pooling + head ----------------
    pool_seg_kernel<<<G, blk, 0, stream>>>(V, batch, pooled, N);
    head_kernel<<<G, dim3(128), 0, stream>>>(pooled, l0_w, l0_b, l0_g, l0_be, l0_m, l0_v,
                                             l1_w, l1_b, outp);
}

// Round 7
// 405.516 us; speedup vs baseline: 15.7408x; 1.0779x over previous
//
#include <hip/hip_runtime.h>
#include <hip/hip_bf16.h>

#define BN_EPS 1e-5f

typedef __attribute__((ext_vector_type(8))) short short8;
typedef __attribute__((ext_vector_type(4))) float f32x4;

__device__ __forceinline__ void gll16(const void* g, void* l) {
    __builtin_amdgcn_global_load_lds(
        (const __attribute__((address_space(1))) unsigned int*)g,
        (__attribute__((address_space(3))) unsigned int*)l, 16, 0, 0);
}

__device__ __forceinline__ unsigned pack_bf2(float a, float b) {
    __hip_bfloat16 ba = __float2bfloat16(a);
    __hip_bfloat16 bb = __float2bfloat16(b);
    return (unsigned)(*(unsigned short*)&ba) | ((unsigned)(*(unsigned short*)&bb) << 16);
}

// ===========================================================================
// CSR construction (graph identical across the 3 layers)
// ===========================================================================
__global__ void hist_kernel(const int* __restrict__ dst, int* __restrict__ off, int E) {
    int e = blockIdx.x * blockDim.x + threadIdx.x;
    if (e < E) atomicAdd(&off[dst[e] + 1], 1);
}

__global__ __launch_bounds__(256) void scan1_kernel(int* __restrict__ data,
                                                    int* __restrict__ sums, int n) {
    __shared__ int sh[256];
    const int t = threadIdx.x;
    const int idx = blockIdx.x * 1024 + t * 4;
    int v[4];
    int s = 0;
#pragma unroll
    for (int j = 0; j < 4; ++j) {
        int x = (idx + j < n) ? data[idx + j] : 0;
        s += x;
        v[j] = s;
    }
    sh[t] = s;
    __syncthreads();
    for (int o = 1; o < 256; o <<= 1) {
        int x = (t >= o) ? sh[t - o] : 0;
        __syncthreads();
        sh[t] += x;
        __syncthreads();
    }
    const int prev = sh[t] - s;
#pragma unroll
    for (int j = 0; j < 4; ++j) {
        if (idx + j < n) data[idx + j] = v[j] + prev;
    }
    if (t == 255) sums[blockIdx.x] = sh[255];
}

__global__ __launch_bounds__(256) void scan2_kernel(int* __restrict__ sums, int nb) {
    __shared__ int sh[256];
    const int t = threadIdx.x;
    sh[t] = (t < nb) ? sums[t] : 0;
    __syncthreads();
    for (int o = 1; o < 256; o <<= 1) {
        int x = (t >= o) ? sh[t - o] : 0;
        __syncthreads();
        sh[t] += x;
        __syncthreads();
    }
    if (t < nb) sums[t] = sh[t];
}

__global__ void scan3_kernel(int* __restrict__ data, const int* __restrict__ sums,
                             int* __restrict__ cursor, int n, int N) {
    int i = blockIdx.x * blockDim.x + threadIdx.x;
    if (i >= n) return;
    int b = i >> 10;
    int v = data[i];
    if (b > 0) { v += sums[b - 1]; data[i] = v; }
    if (i < N) cursor[i] = v;
}

__global__ void fill_kernel(const int* __restrict__ src, const int* __restrict__ dst,
                            int* __restrict__ cursor, int* __restrict__ sorted_src, int E) {
    int e = blockIdx.x * blockDim.x + threadIdx.x;
    if (e >= E) return;
    int p = atomicAdd(&cursor[dst[e]], 1);
    sorted_src[p] = src[e];
}

// ===========================================================================
// prep kernels
// ===========================================================================
__global__ void cvt_x_kernel(const float* __restrict__ x, __hip_bfloat16* __restrict__ xb,
                             int N, int total /* Npad*128 */) {
    int i = blockIdx.x * blockDim.x + threadIdx.x;
    if (i >= total) return;
    int n = i >> 7;
    float v = (n < N) ? x[i] : 0.f;
    xb[i] = __float2bfloat16(v);
}

__global__ void wt_all_kernel(const float* __restrict__ w0, const float* __restrict__ w1,
                              const float* __restrict__ w2, const float* __restrict__ w3,
                              const float* __restrict__ w4, const float* __restrict__ w5,
                              __hip_bfloat16* __restrict__ o0, __hip_bfloat16* __restrict__ o1,
                              __hip_bfloat16* __restrict__ o2, __hip_bfloat16* __restrict__ o3,
                              __hip_bfloat16* __restrict__ o4, __hip_bfloat16* __restrict__ o5) {
    int i = blockIdx.x * blockDim.x + threadIdx.x;
    const int S0 = 256 * 128, S = 256 * 256;
    if (i < S0) {
        int m = i / 128, k = i - m * 128;
        o0[i] = __float2bfloat16(w0[k * 256 + m]);
        return;
    }
    i -= S0;
    int mi = i / S, j = i - mi * S;
    if (mi >= 5) return;
    int m = j >> 8, k = j & 255;
    const float* Wp; __hip_bfloat16* Op;
    switch (mi) {
        case 0: Wp = w1; Op = o1; break;
        case 1: Wp = w2; Op = o2; break;
        case 2: Wp = w3; Op = o3; break;
        case 3: Wp = w4; Op = o4; break;
        default: Wp = w5; Op = o5; break;
    }
    Op[j] = __float2bfloat16(Wp[k * 256 + m]);
}

__global__ void prep_ss_kernel(
    const float* __restrict__ g0, const float* __restrict__ be0, const float* __restrict__ m0,
    const float* __restrict__ v0, const float* __restrict__ b10, const float* __restrict__ b20,
    const float* __restrict__ g1, const float* __restrict__ be1, const float* __restrict__ m1,
    const float* __restrict__ v1, const float* __restrict__ b11, const float* __restrict__ b21,
    const float* __restrict__ g2, const float* __restrict__ be2, const float* __restrict__ m2,
    const float* __restrict__ v2, const float* __restrict__ b12, const float* __restrict__ b22,
    float* __restrict__ ss) {
    const int layer = blockIdx.x;
    const int c = threadIdx.x;
    const float *g, *be, *m, *v, *b1, *b2;
    switch (layer) {
        case 0: g = g0; be = be0; m = m0; v = v0; b1 = b10; b2 = b20; break;
        case 1: g = g1; be = be1; m = m1; v = v1; b1 = b11; b2 = b21; break;
        default: g = g2; be = be2; m = m2; v = v2; b1 = b12; b2 = b22; break;
    }
    float r = rsqrtf(v[c] + BN_EPS);
    float s = g[c] * r;
    ss[(2 * layer) * 512 + c] = s;
    ss[(2 * layer) * 512 + 256 + c] = (b1[c] - m[c]) * s + be[c];
    ss[(2 * layer + 1) * 512 + c] = 1.f;
    ss[(2 * layer + 1) * 512 + 256 + c] = b2[c];
}

// ===========================================================================
// fused aggregate: out[n] = h[n] + sum_{e in CSR(n)} h[src[e]]  (bf16 in/out)
// ===========================================================================
template <int C>
__global__ __launch_bounds__(256) void agg_fused(const __hip_bfloat16* __restrict__ h,
                                                 const int* __restrict__ off,
                                                 const int* __restrict__ ssrc,
                                                 __hip_bfloat16* __restrict__ out, int N) {
    constexpr int L = C / 8;
    int t = blockIdx.x * blockDim.x + threadIdx.x;
    int n = t / L;
    if (n >= N) return;
    int c8 = t - n * L;
    const uint4* hp = (const uint4*)h;

    float acc[8];
    {
        uint4 sv = hp[(size_t)n * L + c8];
        const unsigned u[4] = {sv.x, sv.y, sv.z, sv.w};
#pragma unroll
        for (int j = 0; j < 4; ++j) {
            acc[2 * j]     = __uint_as_float(u[j] << 16);
            acc[2 * j + 1] = __uint_as_float(u[j] & 0xffff0000u);
        }
    }
    const int e0 = off[n], e1 = off[n + 1];
    int e = e0;
    for (; e + 2 <= e1; e += 2) {
        int s0 = ssrc[e], s1 = ssrc[e + 1];
        uint4 a = hp[(size_t)s0 * L + c8];
        uint4 b = hp[(size_t)s1 * L + c8];
        const unsigned ua[4] = {a.x, a.y, a.z, a.w};
        const unsigned ub[4] = {b.x, b.y, b.z, b.w};
#pragma unroll
        for (int j = 0; j < 4; ++j) {
            acc[2 * j]     += __uint_as_float(ua[j] << 16);
            acc[2 * j + 1] += __uint_as_float(ua[j] & 0xffff0000u);
            acc[2 * j]     += __uint_as_float(ub[j] << 16);
            acc[2 * j + 1] += __uint_as_float(ub[j] & 0xffff0000u);
        }
    }
    if (e < e1) {
        int s0 = ssrc[e];
        uint4 a = hp[(size_t)s0 * L + c8];
        const unsigned ua[4] = {a.x, a.y, a.z, a.w};
#pragma unroll
        for (int j = 0; j < 4; ++j) {
            acc[2 * j]     += __uint_as_float(ua[j] << 16);
            acc[2 * j + 1] += __uint_as_float(ua[j] & 0xffff0000u);
        }
    }
    unsigned o[4];
#pragma unroll
    for (int j = 0; j < 4; ++j) o[j] = pack_bf2(acc[2 * j], acc[2 * j + 1]);
    ((uint4*)out)[(size_t)n * L + c8] = make_uint4(o[0], o[1], o[2], o[3]);
}

// ===========================================================================
// fused MLP layer, 64-row panel, full 256-col width, 8 waves (2 row-halves x
// 4 col-quarters), wave tile 32x64. LDS = 32KB A/T/C buffer + 32KB W tile =
// 64KB -> 2 blocks/CU (launch_bounds(512,4)). Single-buffered W: TLP hides
// the stage stalls.  Both GEMMs swapped: mfma(Wfrag, Xfrag) so lanes hold 4
// consecutive output cols -> packed 8B LDS writes for T and C; C then stored
// coalesced via LDS (fixes 2x HBM write amplification of scalar bf16 stores).
// In-place safe (block reads only its own 64 rows, writes at the very end).
// ===========================================================================
template <int K1>
__global__ __launch_bounds__(512, 4) void mlp_fused(
    const __hip_bfloat16* __restrict__ A,
    const __hip_bfloat16* __restrict__ W1t,   // [256][K1] bf16 (W1 transposed)
    const __hip_bfloat16* __restrict__ W2t,   // [256][256] bf16
    const float* __restrict__ ss1, const float* __restrict__ ss2,
    __hip_bfloat16* __restrict__ C) {
    __shared__ __align__(16) char bufAT[32 * 1024];  // A panel -> T -> C staging
    __shared__ __align__(16) char bufW[32 * 1024];   // one 64k x 256c W tile

    const int tid = threadIdx.x;
    const int l   = tid & 63;
    const int w   = tid >> 6;        // 0..7
    const int wr  = w >> 2;          // 0..1: rows wr*32..+31
    const int wc  = w & 3;           // 0..3: cols wc*64..+63
    const size_t row0 = (size_t)blockIdx.x * 64;

    constexpr int ROWB = K1 * 2;     // A row bytes
    constexpr int NT1  = K1 / 64;    // GEMM1 K-tiles
    const int lswz = (l & 7) << 4;   // frag-read XOR ((row&7)<<4 with row&7==l&7)

    // ---- stage A panel (pre-swizzled source, linear LDS dest) ----
    {
        const char* Ab = (const char*)(A + row0 * K1);
        constexpr int NIA = 64 * ROWB / 1024;  // K=256: 32, K=128: 16
        constexpr int RPI = 1024 / ROWB;       // rows per gll16 instr
#pragma unroll
        for (int i = w; i < NIA; i += 8) {
            int row = i * RPI + (l * 16) / ROWB;
            int byt = ((l * 16) % ROWB) ^ ((row & 7) << 4);
            gll16(Ab + (size_t)row * ROWB + byt, bufAT + i * 1024);
        }
    }
    // ---- W tile stager: k-window [t*64, t*64+64) of Wsrc[256][Krow2/2] ----
    auto stageW = [&](const __hip_bfloat16* Wsrc, int Krow2, int t) {
#pragma unroll
        for (int i = w; i < 32; i += 8) {
            int c = i * 8 + (l >> 3);
            int byt = ((l & 7) * 16) ^ ((l >> 3) << 4);  // (c&7)==(l>>3)
            gll16((const char*)Wsrc + (size_t)c * Krow2 + t * 128 + byt, bufW + i * 1024);
        }
    };
    stageW(W1t, ROWB, 0);
    asm volatile("s_waitcnt vmcnt(0)" ::: "memory");
    __syncthreads();

    // ================= GEMM1: T = A @ W1 (swapped operands) =================
    f32x4 acc1[4][2] = {};  // [mi: W1-col frag][nj: row frag]
#pragma unroll
    for (int t = 0; t < NT1; ++t) {
#pragma unroll
        for (int k0 = 0; k0 < 2; ++k0) {
            short8 wf[4], af[2];
            const int wbyt = (k0 * 64 + (l >> 4) * 16) ^ lswz;
            const int abyt = (t * 128 + k0 * 64 + (l >> 4) * 16) ^ lswz;
#pragma unroll
            for (int i = 0; i < 4; ++i)
                wf[i] = *(const short8*)(bufW + (wc * 64 + i * 16 + (l & 15)) * 128 + wbyt);
#pragma unroll
            for (int i = 0; i < 2; ++i)
                af[i] = *(const short8*)(bufAT + (wr * 32 + i * 16 + (l & 15)) * ROWB + abyt);
#pragma unroll
            for (int mi = 0; mi < 4; ++mi)
#pragma unroll
                for (int nj = 0; nj < 2; ++nj)
                    acc1[mi][nj] = __builtin_amdgcn_mfma_f32_16x16x32_bf16(
                        wf[mi], af[nj], acc1[mi][nj], 0, 0, 0);
        }
        __syncthreads();  // all waves done reading bufW (and, at last t, bufAT)
        if (t + 1 < NT1) {
            stageW(W1t, ROWB, t + 1);
            asm volatile("s_waitcnt vmcnt(0)" ::: "memory");
            __syncthreads();
        }
    }

    // ---- issue W2 tile 0 stage, overlap with T-write into bufAT ----
    stageW(W2t, 512, 0);
    // T[n = wr*32+nj*16+(l&15)][m0..m0+3], m0 = wc*64+mi*16+(l>>4)*4
#pragma unroll
    for (int mi = 0; mi < 4; ++mi) {
        const int m0 = wc * 64 + mi * 16 + (l >> 4) * 4;
        const float4 s4 = *(const float4*)(ss1 + m0);
        const float4 h4 = *(const float4*)(ss1 + 256 + m0);
        const int byt = (m0 * 2) ^ lswz;
#pragma unroll
        for (int nj = 0; nj < 2; ++nj) {
            const int n = wr * 32 + nj * 16 + (l & 15);
            const float v0 = fmaxf(acc1[mi][nj][0] * s4.x + h4.x, 0.f);
            const float v1 = fmaxf(acc1[mi][nj][1] * s4.y + h4.y, 0.f);
            const float v2 = fmaxf(acc1[mi][nj][2] * s4.z + h4.z, 0.f);
            const float v3 = fmaxf(acc1[mi][nj][3] * s4.w + h4.w, 0.f);
            *(uint2*)(bufAT + n * 512 + byt) = make_uint2(pack_bf2(v0, v1), pack_bf2(v2, v3));
        }
    }
    asm volatile("s_waitcnt vmcnt(0)" ::: "memory");
    __syncthreads();  // T + W2 tile 0 ready

    // ================= GEMM2: C = T @ W2 (swapped operands) =================
    f32x4 acc2[4][2] = {};  // [ni: W2-col frag][mj: row frag]
#pragma unroll
    for (int s = 0; s < 4; ++s) {
#pragma unroll
        for (int k0 = 0; k0 < 2; ++k0) {
            short8 wf[4], tf[2];
            const int wbyt = (k0 * 64 + (l >> 4) * 16) ^ lswz;
            const int tbyt = (s * 128 + k0 * 64 + (l >> 4) * 16) ^ lswz;
#pragma unroll
            for (int i = 0; i < 4; ++i)
                wf[i] = *(const short8*)(bufW + (wc * 64 + i * 16 + (l & 15)) * 128 + wbyt);
#pragma unroll
            for (int i = 0; i < 2; ++i)
                tf[i] = *(const short8*)(bufAT + (wr * 32 + i * 16 + (l & 15)) * 512 + tbyt);
#pragma unroll
            for (int ni = 0; ni < 4; ++ni)
#pragma unroll
                for (int mj = 0; mj < 2; ++mj)
                    acc2[ni][mj] = __builtin_amdgcn_mfma_f32_16x16x32_bf16(
                        wf[ni], tf[mj], acc2[ni][mj], 0, 0, 0);
        }
        __syncthreads();
        if (s < 3) {
            stageW(W2t, 512, s + 1);
            asm volatile("s_waitcnt vmcnt(0)" ::: "memory");
            __syncthreads();
        }
    }

    // ---- C epilogue into LDS (bufAT; T fully consumed), packed 8B writes ----
#pragma unroll
    for (int ni = 0; ni < 4; ++ni) {
        const int c0 = wc * 64 + ni * 16 + (l >> 4) * 4;
        const float4 s4 = *(const float4*)(ss2 + c0);
        const float4 h4 = *(const float4*)(ss2 + 256 + c0);
        const int byt = (c0 * 2) ^ lswz;
#pragma unroll
        for (int mj = 0; mj < 2; ++mj) {
            const int n = wr * 32 + mj * 16 + (l & 15);
            const float v0 = fmaxf(acc2[ni][mj][0] * s4.x + h4.x, 0.f);
            const float v1 = fmaxf(acc2[ni][mj][1] * s4.y + h4.y, 0.f);
            const float v2 = fmaxf(acc2[ni][mj][2] * s4.z + h4.z, 0.f);
            const float v3 = fmaxf(acc2[ni][mj][3] * s4.w + h4.w, 0.f);
            *(uint2*)(bufAT + n * 512 + byt) = make_uint2(pack_bf2(v0, v1), pack_bf2(v2, v3));
        }
    }
    __syncthreads();

    // ---- coalesced store: 64 rows x 512B = 32KB, dwordx4 ----
    {
        char* Cb = (char*)C + row0 * 512;
#pragma unroll
        for (int q = tid; q < 2048; q += 512) {
            const int n = q >> 5;
            const int slot = (q & 31) * 16;
            uint4 v = *(const uint4*)(bufAT + n * 512 + (slot ^ ((n & 7) << 4)));
            *(uint4*)(Cb + q * 16) = v;
        }
    }
}

// ===========================================================================
// segmented pool (bf16 in, fp32 out), one block per graph
// ===========================================================================
__device__ __forceinline__ int lower_bound_dev(const int* __restrict__ a, int n, int key) {
    int lo = 0, hi = n;
    while (lo < hi) {
        int mid = (lo + hi) >> 1;
        if (a[mid] < key) lo = mid + 1; else hi = mid;
    }
    return lo;
}

__global__ __launch_bounds__(256) void pool_seg_kernel(const __hip_bfloat16* __restrict__ h,
                                                       const int* __restrict__ batch,
                                                       float* __restrict__ pooled, int N) {
    __shared__ int seg[2];
    const int g = blockIdx.x;
    if (threadIdx.x == 0) seg[0] = lower_bound_dev(batch, N, g);
    if (threadIdx.x == 1) seg[1] = lower_bound_dev(batch, N, g + 1);
    __syncthreads();
    const int c = threadIdx.x;
    float acc = 0.f;
    for (int n = seg[0]; n < seg[1]; ++n) acc += __bfloat162float(h[(size_t)n * 256 + c]);
    pooled[(size_t)g * 256 + c] = acc;
}

// ===========================================================================
// head
// ===========================================================================
__global__ __launch_bounds__(128) void head_kernel(
    const float* __restrict__ pooled,
    const float* __restrict__ w0, const float* __restrict__ b0,
    const float* __restrict__ g, const float* __restrict__ be,
    const float* __restrict__ m, const float* __restrict__ v,
    const float* __restrict__ w1, const float* __restrict__ b1,
    float* __restrict__ out) {
    __shared__ float row[256];
    __shared__ float red[128];
    const int gid = blockIdx.x;
    const int j = threadIdx.x;

    row[j]       = pooled[(size_t)gid * 256 + j];
    row[j + 128] = pooled[(size_t)gid * 256 + 128 + j];
    __syncthreads();

    float acc = b0[j];
#pragma unroll 8
    for (int k = 0; k < 256; ++k) acc += row[k] * w0[k * 128 + j];

    float h = g[j] * (acc - m[j]) * rsqrtf(v[j] + BN_EPS) + be[j];
    h = fmaxf(h, 0.f) * w1[j];
    red[j] = h;
    __syncthreads();
    for (int s = 64; s > 0; s >>= 1) {
        if (j < s) red[j] += red[j + s];
        __syncthreads();
    }
    if (j == 0) out[gid] = red[0] + b1[0];
}

// ===========================================================================
// launch
// ===========================================================================
extern "C" void kernel_launch(void* const* d_in, const int* in_sizes, int n_in,
                              void* d_out, int out_size, void* d_ws, size_t ws_size,
                              hipStream_t stream) {
    const float* x    = (const float*)d_in[0];
    const int* eidx   = (const int*)d_in[1];
    const int* batch  = (const int*)d_in[2];

    const int N = in_sizes[0] / 128;
    const int E = in_sizes[1] / 2;
    const int G = out_size;

    const int* src = eidx;
    const int* dst = eidx + E;

    const float* cw1[3]; const float* cb1[3]; const float* cg[3]; const float* cbe[3];
    const float* cm[3];  const float* cv[3];  const float* cw2[3]; const float* cb2[3];
    for (int i = 0; i < 3; ++i) {
        int b = 3 + i * 8;
        cw1[i] = (const float*)d_in[b + 0];
        cb1[i] = (const float*)d_in[b + 1];
        cg[i]  = (const float*)d_in[b + 2];
        cbe[i] = (const float*)d_in[b + 3];
        cm[i]  = (const float*)d_in[b + 4];
        cv[i]  = (const float*)d_in[b + 5];
        cw2[i] = (const float*)d_in[b + 6];
        cb2[i] = (const float*)d_in[b + 7];
    }
    const float* l0_w  = (const float*)d_in[27];
    const float* l0_b  = (const float*)d_in[28];
    const float* l0_g  = (const float*)d_in[29];
    const float* l0_be = (const float*)d_in[30];
    const float* l0_m  = (const float*)d_in[31];
    const float* l0_v  = (const float*)d_in[32];
    const float* l1_w  = (const float*)d_in[33];
    const float* l1_b  = (const float*)d_in[34];

    float* outp = (float*)d_out;

    // ---- workspace layout ----
    const int nrb  = (N + 127) / 128;
    const int Npad = nrb * 128;
    const int nrb64 = Npad / 64;
    const size_t SB = (size_t)Npad * 256 * 2;   // bf16 [Npad][256]
    const size_t XB = (size_t)Npad * 128 * 2;   // bf16 [Npad][128]
    const size_t PB = (size_t)G * 256 * 4;
    const size_t WTB = (size_t)256 * 256 * 2;

    char* ws = (char*)d_ws;
    size_t o = 0;
    __hip_bfloat16* U  = (__hip_bfloat16*)(ws + o); o += SB;
    __hip_bfloat16* V  = (__hip_bfloat16*)(ws + o); o += SB;
    __hip_bfloat16* xb = (__hip_bfloat16*)(ws + o); o += XB;
    float* pooled      = (float*)(ws + o);       o += PB;
    __hip_bfloat16* wt[6];
    for (int i = 0; i < 6; ++i) { wt[i] = (__hip_bfloat16*)(ws + o); o += WTB; }
    float* ss          = (float*)(ws + o);       o += 6 * 512 * 4;
    int* csr_off    = (int*)(ws + o); o += (size_t)(N + 1) * 4;
    int* cursor     = (int*)(ws + o); o += (size_t)N * 4;
    int* sorted_src = (int*)(ws + o); o += (size_t)E * 4;
    int* sums       = (int*)(ws + o); o += 256 * 4;
    if (ws_size < o) return;  // clean failure instead of page fault

    const dim3 blk(256);

    // ---- prep ----
    {
        int total = Npad * 128;
        cvt_x_kernel<<<(total + 255) / 256, blk, 0, stream>>>(x, xb, N, total);
    }
    {
        int total = 256 * 128 + 5 * 256 * 256;
        wt_all_kernel<<<(total + 255) / 256, blk, 0, stream>>>(
            cw1[0], cw2[0], cw1[1], cw2[1], cw1[2], cw2[2],
            wt[0], wt[1], wt[2], wt[3], wt[4], wt[5]);
    }
    prep_ss_kernel<<<3, blk, 0, stream>>>(
        cg[0], cbe[0], cm[0], cv[0], cb1[0], cb2[0],
        cg[1], cbe[1], cm[1], cv[1], cb1[1], cb2[1],
        cg[2], cbe[2], cm[2], cv[2], cb1[2], cb2[2], ss);

    // ---- CSR build ----
    {
        const int n_off = N + 1;
        hipMemsetAsync(csr_off, 0, (size_t)n_off * sizeof(int), stream);
        hist_kernel<<<(E + 255) / 256, blk, 0, stream>>>(dst, csr_off, E);
        const int nb = (n_off + 1023) / 1024;
        scan1_kernel<<<nb, blk, 0, stream>>>(csr_off, sums, n_off);
        scan2_kernel<<<1, blk, 0, stream>>>(sums, nb);
        scan3_kernel<<<(n_off + 255) / 256, blk, 0, stream>>>(csr_off, sums, cursor, n_off, N);
        fill_kernel<<<(E + 255) / 256, blk, 0, stream>>>(src, dst, cursor, sorted_src, E);
    }

    auto SS = [&](int i) { return ss + i * 512; };

    // ---------------- layer 0 (128 -> 256): agg xb->U, mlp U->V ----
    {
        int total = N * 16;
        agg_fused<128><<<(total + 255) / 256, blk, 0, stream>>>(xb, csr_off, sorted_src, U, N);
    }
    mlp_fused<128><<<nrb64, dim3(512), 0, stream>>>(U, wt[0], wt[1], SS(0), SS(1), V);

    // ---------------- layer 1: agg V->U, mlp U->U (in-place) ----
    {
        int total = N * 32;
        agg_fused<256><<<(total + 255) / 256, blk, 0, stream>>>(V, csr_off, sorted_src, U, N);
    }
    mlp_fused<256><<<nrb64, dim3(512), 0, stream>>>(U, wt[2], wt[3], SS(2), SS(3), U);

    // ---------------- layer 2: agg U->V, mlp V->V (in-place) ----
    {
        int total = N * 32;
        agg_fused<256><<<(total + 255) / 256, blk, 0, stream>>>(U, csr_off, sorted_src, V, N);
    }
    mlp_fused<256><<<nrb64, dim3(512), 0, stream>>>(V, wt[4], wt[5], SS(4), SS(5), V);

    // ---------------- pooling + head ----------------
    pool_seg_kernel<<<G, blk, 0, stream>>>(V, batch, pooled, N);
    head_kernel<<<G, dim3(128), 0, stream>>>(pooled, l0_w, l0_b, l0_g, l0_be, l0_m, l0_v,
                                             l1_w, l1_b, outp);
}